// Round 8
// baseline (431.328 us; speedup 1.0000x reference)
//
#include <hip/hip_runtime.h>
#include <hip/hip_cooperative_groups.h>
#include <math.h>

namespace cg = cooperative_groups;

// Problem dims
#define BB  8
#define SS  512
#define EE  128
#define HH  16
#define LL  4
#define FF  512
#define CC  10

typedef _Float16 h2 __attribute__((ext_vector_type(2)));
typedef _Float16 h4 __attribute__((ext_vector_type(4)));
typedef float f32x16 __attribute__((ext_vector_type(16)));

// ---- shared memory union across phases (~56.9 KB) ----
struct AttnS {
    _Float16 encA[2][SS][4];    // A/B operand halves
    _Float16 encT[9][524];      // V columns (+ones)
};
struct FusedS {
    _Float16 oA[32][132];       // A-frags Wo GEMM (rows 0-15 real)
    _Float16 hid16[32][516];    // A-frags W2 GEMM (rows 0-15 real)
    float vL[16][128];          // GEMM C tile
    float hL[16][128];          // residual / v2
    float measL[16][4];
    float meanL[16], rstdL[16];
};
struct HeadS {
    float4 red[8][32];
    float pooled[EE];
};
union SharedU {
    AttnS a;
    FusedS f;
    HeadS hd;
};

// ---------------------------------------------------------------------------
__device__ __forceinline__ void ring_from_x(
    const float4 xa, const float4 xb, const float4 tha, const float4 thb,
    float* o)
{
    float c0 = cosf(xa.x + tha.x), c1 = cosf(xa.y + tha.y),
          c2 = cosf(xa.z + tha.z), c3 = cosf(xa.w + tha.w),
          c4 = cosf(xb.x + thb.x), c5 = cosf(xb.y + thb.y),
          c6 = cosf(xb.z + thb.z), c7 = cosf(xb.w + thb.w);
    o[0] = c1 * c2 * c3 * c4 * c5 * c6 * c7;   // z0 (no c0)
    float cum = c0;
    cum *= c1; o[1] = cum;  cum *= c2; o[2] = cum;
    cum *= c3; o[3] = cum;  cum *= c4; o[4] = cum;
    cum *= c5; o[5] = cum;  cum *= c6; o[6] = cum;
    cum *= c7; o[7] = cum;
}

// ---------------------------------------------------------------------------
// Mega kernel: prep -> L x (attn -> fused) -> head. 256 blocks x 256 thr,
// cooperative. 1 block/CU co-residency is satisfiable for any VGPR/LDS.
// ---------------------------------------------------------------------------
__global__ __launch_bounds__(256, 2) void mega_kernel(
    const int* __restrict__ tokens, const float* __restrict__ emb,
    const float* __restrict__ attn_theta, const float* __restrict__ ffn_theta,
    const float* __restrict__ Wo, const float* __restrict__ W1,
    const float* __restrict__ W2,
    const float* __restrict__ ln1g, const float* __restrict__ ln1b,
    const float* __restrict__ ln2g, const float* __restrict__ ln2b,
    const float* __restrict__ Wc, const float* __restrict__ bc,
    float* __restrict__ out,
    float* __restrict__ h, float* __restrict__ o,
    _Float16* __restrict__ WoB, _Float16* __restrict__ W2B)
{
    cg::grid_group grid = cg::this_grid();
    __shared__ SharedU su;

    int tid  = threadIdx.x;
    int blk  = blockIdx.x;
    int gtid = blk * 256 + tid;              // 0..65535

    // ================= phase 0: embed + weight repacks =================
    {
        for (int i = gtid; i < BB * SS * EE; i += 65536) {
            int e  = i & 127;
            int bs = i >> 7;
            int s  = bs & 511;
            int tok = tokens[bs];
            int half = e >> 1;
            float ang = (float)s * expf(-0.07195578415606394f * (float)(2 * half));
            float pe  = (e & 1) ? cosf(ang) : sinf(ang);
            h[i] = emb[(size_t)tok * EE + e] + pe;
        }
        // WoB: [l][kt(16)][nt(4)][lane(64)][jj(4)]  (65536 = 1/thread)
        {
            int i = gtid;
            int jj = i & 3, lane = (i >> 2) & 63, nt = (i >> 8) & 3,
                kt = (i >> 10) & 15, l = i >> 14;
            int e = nt * 32 + (lane & 31);
            int k = kt * 8 + (lane >> 5) * 4 + jj;
            WoB[i] = (_Float16)Wo[((size_t)l * EE + e) * EE + k];
        }
        // W2B: [l][kt(64)][nt(4)][lane(64)][jj(4)]  (262144 = 4/thread)
        for (int i = gtid; i < LL * 65536; i += 65536) {
            int jj = i & 3, lane = (i >> 2) & 63, nt = (i >> 8) & 3,
                kt = (i >> 10) & 63, l = i >> 16;
            int e = nt * 32 + (lane & 31);
            int j = kt * 8 + (lane >> 5) * 4 + jj;
            W2B[i] = (_Float16)W2[((size_t)l * EE + e) * FF + j];
        }
    }
    grid.sync();

    int lane = tid & 63, wv = tid >> 6;
    int col  = lane & 31, hf = lane >> 5;

    for (int l = 0; l < LL; l++) {
        const float*    th8  = attn_theta + (size_t)l * 8;
        const _Float16* WoBl = WoB + (size_t)l * 16384;
        const _Float16* W2Bl = W2B + (size_t)l * 65536;
        const float*    W1l  = W1 + (size_t)l * 2048;
        const float*    fthl = ffn_theta + (size_t)l * 4;
        const float*    g1p  = ln1g + (size_t)l * EE;
        const float*    b1p  = ln1b + (size_t)l * EE;
        const float*    g2p  = ln2g + (size_t)l * EE;
        const float*    b2p  = ln2b + (size_t)l * EE;

        // ============ attn phase: block = (bh, qhalf); 2 q-tiles ILP ============
        {
            int bh = blk >> 1, qh = blk & 1;
            int b = bh >> 4, hh = bh & 15;

            float4 tha = ((const float4*)th8)[0];
            float4 thb = ((const float4*)th8)[1];

#pragma unroll
            for (int kk = 0; kk < 2; kk++) {
                int k = tid + kk * 256;
                const float* hp = h + ((size_t)(b * SS + k) * EE + hh * 8);
                float oo[8];
                ring_from_x(*(const float4*)hp, *(const float4*)(hp + 4), tha, thb, oo);
                h4 lo = {(_Float16)oo[0], (_Float16)oo[1], (_Float16)oo[2], (_Float16)oo[3]};
                h4 hi = {(_Float16)oo[4], (_Float16)oo[5], (_Float16)oo[6], (_Float16)oo[7]};
                *(h4*)&su.a.encA[0][k][0] = lo;
                *(h4*)&su.a.encA[1][k][0] = hi;
#pragma unroll
                for (int d = 0; d < 8; d++) su.a.encT[d][k] = (_Float16)oo[d];
                su.a.encT[8][k] = (_Float16)1.0f;
            }
            __syncthreads();

            int qt0 = qh * 256 + wv * 32;         // second tile at qt0+128
            h4 bq0 = *(const h4*)&su.a.encA[hf][qt0 + col][0];
            h4 bq1 = *(const h4*)&su.a.encA[hf][qt0 + 128 + col][0];

            const float SC = 0.35355339059327373f * 1.4426950408889634f;
            f32x16 O0 = {}, O1 = {};
            for (int kt = 0; kt < SS; kt += 32) {
                h4 ak = *(const h4*)&su.a.encA[hf][kt + col][0];
                f32x16 Cz = {};
                f32x16 C0 = __builtin_amdgcn_mfma_f32_32x32x8f16(ak, bq0, Cz, 0, 0, 0);
                f32x16 C1 = __builtin_amdgcn_mfma_f32_32x32x8f16(ak, bq1, Cz, 0, 0, 0);
                h2 p0[8], p1[8];
#pragma unroll
                for (int r = 0; r < 16; r += 2) {
                    float a0 = C0[r] * SC, a1 = C0[r + 1] * SC;
                    float b0 = C1[r] * SC, b1 = C1[r + 1] * SC;
                    float w00, w01, w10, w11;
                    asm("v_exp_f32 %0, %1" : "=v"(w00) : "v"(a0));
                    asm("v_exp_f32 %0, %1" : "=v"(w01) : "v"(a1));
                    asm("v_exp_f32 %0, %1" : "=v"(w10) : "v"(b0));
                    asm("v_exp_f32 %0, %1" : "=v"(w11) : "v"(b1));
                    p0[r >> 1] = (h2)__builtin_amdgcn_cvt_pkrtz(w00, w01);
                    p1[r >> 1] = (h2)__builtin_amdgcn_cvt_pkrtz(w10, w11);
                }
#pragma unroll
                for (int j = 0; j < 4; j++) {
                    h4 bv = {};
                    if (col <= 8)
                        bv = *(const h4*)&su.a.encT[col][kt + 8 * j + 4 * hf];
                    h4 a0 = {p0[2 * j][0], p0[2 * j][1], p0[2 * j + 1][0], p0[2 * j + 1][1]};
                    h4 a1 = {p1[2 * j][0], p1[2 * j][1], p1[2 * j + 1][0], p1[2 * j + 1][1]};
                    O0 = __builtin_amdgcn_mfma_f32_32x32x8f16(a0, bv, O0, 0, 0, 0);
                    O1 = __builtin_amdgcn_mfma_f32_32x32x8f16(a1, bv, O1, 0, 0, 0);
                }
            }

#pragma unroll
            for (int r = 0; r < 16; r++) {
                float rs0 = __shfl(O0[r], 8, 32);
                float rs1 = __shfl(O1[r], 8, 32);
                if (col < 8) {
                    int row = (r & 3) + 8 * (r >> 2) + 4 * hf;
                    o[((size_t)(b * SS + qt0 + row)) * EE + hh * 8 + col] =
                        O0[r] * __builtin_amdgcn_rcpf(rs0);
                    o[((size_t)(b * SS + qt0 + 128 + row)) * EE + hh * 8 + col] =
                        O1[r] * __builtin_amdgcn_rcpf(rs1);
                }
            }
        }
        grid.sync();

        // ============ fused phase: 16 tokens/block, 4 waves, full K ============
        {
            int t0 = blk * 16;
            for (int i = tid; i < 512; i += 256) {
                int t = i >> 5, c4 = i & 31;
                float4 ov = ((const float4*)o)[(size_t)(t0 + t) * 32 + c4];
                h4 hv = {(_Float16)ov.x, (_Float16)ov.y, (_Float16)ov.z, (_Float16)ov.w};
                *(h4*)&su.f.oA[t][c4 * 4] = hv;
                float4 hvf = ((const float4*)h)[(size_t)(t0 + t) * 32 + c4];
                *(float4*)&su.f.hL[t][c4 * 4] = hvf;
            }
            __syncthreads();

            int nt = wv, arow = lane & 31;

            // ---- Wo GEMM: K=128, dual accumulators ----
            f32x16 Ca = {}, Cb = {};
            for (int kt = 0; kt < 16; kt += 2) {
                h4 a0 = *(const h4*)&su.f.oA[arow][kt * 8 + hf * 4];
                h4 b0 = *(const h4*)&WoBl[((size_t)((kt * 4 + nt) * 64 + lane)) * 4];
                Ca = __builtin_amdgcn_mfma_f32_32x32x8f16(a0, b0, Ca, 0, 0, 0);
                h4 a1 = *(const h4*)&su.f.oA[arow][(kt + 1) * 8 + hf * 4];
                h4 b1 = *(const h4*)&WoBl[((size_t)(((kt + 1) * 4 + nt) * 64 + lane)) * 4];
                Cb = __builtin_amdgcn_mfma_f32_32x32x8f16(a1, b1, Cb, 0, 0, 0);
            }
#pragma unroll
            for (int r = 0; r < 8; r++)
                su.f.vL[(r & 3) + 8 * (r >> 2) + 4 * hf][nt * 32 + col] = Ca[r] + Cb[r];
            __syncthreads();

            // ---- LN1 stats: 16 lanes/token ----
            int tt = tid >> 4, l16 = tid & 15;
            {
                float sm = 0.f, sq = 0.f;
#pragma unroll
                for (int i = 0; i < 8; i++) {
                    float x = su.f.vL[tt][l16 + 16 * i] + su.f.hL[tt][l16 + 16 * i];
                    sm += x; sq += x * x;
                }
#pragma unroll
                for (int ofs = 8; ofs >= 1; ofs >>= 1) {
                    sm += __shfl_xor(sm, ofs);
                    sq += __shfl_xor(sq, ofs);
                }
                if (l16 == 0) {
                    float mu = sm * (1.f / 128.f);
                    su.f.meanL[tt] = mu;
                    su.f.rstdL[tt] = rsqrtf(sq * (1.f / 128.f) - mu * mu + 1e-5f);
                }
            }
            __syncthreads();

            // ---- h1 (regs, 8 tokens/thread) + meas ----
            int e = tid & 127, g = tid >> 7;      // g in {0,1}
            float ge1 = g1p[e], be1 = b1p[e];
            float h1v[8];
#pragma unroll
            for (int t = 0; t < 8; t++) {
                int idx = g * 8 + t;
                float v = su.f.vL[idx][e] + su.f.hL[idx][e];
                h1v[t] = (v - su.f.meanL[idx]) * su.f.rstdL[idx] * ge1 + be1;
            }
            if (e < 4) {
                float cth = cosf(fthl[e]);
#pragma unroll
                for (int t = 0; t < 8; t++)
                    su.f.measL[g * 8 + t][e] = cosf(h1v[t]) * cth;
            }
            __syncthreads();

            // ---- hidden = relu(meas @ W1^T) -> f16 A layout ----
#pragma unroll
            for (int jj = 0; jj < 2; jj++) {
                int j = jj * 256 + tid;
                float4 w1v = ((const float4*)W1l)[j];
#pragma unroll
                for (int t = 0; t < 16; t++) {
                    float4 mv = *(const float4*)&su.f.measL[t][0];
                    float hv = mv.x * w1v.x + mv.y * w1v.y + mv.z * w1v.z + mv.w * w1v.w;
                    su.f.hid16[t][j] = (_Float16)fmaxf(hv, 0.f);
                }
            }
            __syncthreads();

            // ---- W2 GEMM: K=512, dual accumulators ----
            f32x16 Fa = {}, Fb = {};
            for (int kt = 0; kt < 64; kt += 2) {
                h4 a0 = *(const h4*)&su.f.hid16[arow][kt * 8 + hf * 4];
                h4 b0 = *(const h4*)&W2Bl[((size_t)((kt * 4 + nt) * 64 + lane)) * 4];
                Fa = __builtin_amdgcn_mfma_f32_32x32x8f16(a0, b0, Fa, 0, 0, 0);
                h4 a1 = *(const h4*)&su.f.hid16[arow][(kt + 1) * 8 + hf * 4];
                h4 b1 = *(const h4*)&W2Bl[((size_t)(((kt + 1) * 4 + nt) * 64 + lane)) * 4];
                Fb = __builtin_amdgcn_mfma_f32_32x32x8f16(a1, b1, Fb, 0, 0, 0);
            }
#pragma unroll
            for (int r = 0; r < 8; r++)
                su.f.vL[(r & 3) + 8 * (r >> 2) + 4 * hf][nt * 32 + col] = Fa[r] + Fb[r];
            __syncthreads();

            // ---- v2 = h1 + f -> hL; LN2; write h ----
            float v2[8];
#pragma unroll
            for (int t = 0; t < 8; t++) {
                int idx = g * 8 + t;
                v2[t] = h1v[t] + su.f.vL[idx][e];
                su.f.hL[idx][e] = v2[t];
            }
            __syncthreads();
            {
                float sm = 0.f, sq = 0.f;
#pragma unroll
                for (int i = 0; i < 8; i++) {
                    float x = su.f.hL[tt][l16 + 16 * i];
                    sm += x; sq += x * x;
                }
#pragma unroll
                for (int ofs = 8; ofs >= 1; ofs >>= 1) {
                    sm += __shfl_xor(sm, ofs);
                    sq += __shfl_xor(sq, ofs);
                }
                if (l16 == 0) {
                    float mu = sm * (1.f / 128.f);
                    su.f.meanL[tt] = mu;
                    su.f.rstdL[tt] = rsqrtf(sq * (1.f / 128.f) - mu * mu + 1e-5f);
                }
            }
            __syncthreads();
            float ge2 = g2p[e], be2 = b2p[e];
#pragma unroll
            for (int t = 0; t < 8; t++) {
                int idx = g * 8 + t;
                h[(size_t)(t0 + idx) * 128 + e] =
                    (v2[t] - su.f.meanL[idx]) * su.f.rstdL[idx] * ge2 + be2;
            }
        }
        grid.sync();
    }

    // ================= head phase: blocks 0..7 =================
    if (blk < BB) {
        int b = blk;
        int eq = tid & 31, sg = tid >> 5;
        const float4* h4p = (const float4*)h + (size_t)b * SS * 32;
        float4 acc = make_float4(0, 0, 0, 0);
        for (int r = 0; r < 64; r++) {
            int s = r * 8 + sg;
            float4 x = h4p[(size_t)s * 32 + eq];
            acc.x += x.x; acc.y += x.y; acc.z += x.z; acc.w += x.w;
        }
        su.hd.red[sg][eq] = acc;
        __syncthreads();
        if (sg == 0) {
            float4 a = su.hd.red[0][eq];
#pragma unroll
            for (int i = 1; i < 8; i++) {
                float4 x = su.hd.red[i][eq];
                a.x += x.x; a.y += x.y; a.z += x.z; a.w += x.w;
            }
            const float s = 1.f / (float)SS;
            *(float4*)&su.hd.pooled[eq * 4] =
                make_float4(a.x * s, a.y * s, a.z * s, a.w * s);
        }
        __syncthreads();
        if (tid < 160) {
            int c = tid >> 4, l16h = tid & 15;
            float p = 0.f;
#pragma unroll
            for (int i = 0; i < 8; i++) {
                int k = l16h + i * 16;
                p += su.hd.pooled[k] * Wc[(size_t)c * EE + k];
            }
#pragma unroll
            for (int ofs = 8; ofs >= 1; ofs >>= 1) p += __shfl_xor(p, ofs);
            if (l16h == 0) out[b * CC + c] = p + bc[c];
        }
    }
}

// ===========================================================================
// FALLBACK PATH — round-6 proven kernels (used only if cooperative launch
// is rejected by the runtime).
// ===========================================================================
__global__ __launch_bounds__(256) void prep_kernel(
    const int* __restrict__ tokens, const float* __restrict__ emb,
    const float* __restrict__ Wo, const float* __restrict__ W2,
    float* __restrict__ h, _Float16* __restrict__ WoB, _Float16* __restrict__ W2B)
{
    int i = blockIdx.x * 256 + threadIdx.x;
    {
        int e  = i & 127;
        int bs = i >> 7;
        int s  = bs & 511;
        int tok = tokens[bs];
        int half = e >> 1;
        float ang = (float)s * expf(-0.07195578415606394f * (float)(2 * half));
        float pe  = (e & 1) ? cosf(ang) : sinf(ang);
        h[i] = emb[(size_t)tok * EE + e] + pe;
    }
    if (i < LL * 16384) {
        int jj = i & 3, lane = (i >> 2) & 63, nt = (i >> 8) & 3,
            kt = (i >> 10) & 15, l = i >> 14;
        int e = nt * 32 + (lane & 31);
        int k = kt * 8 + (lane >> 5) * 4 + jj;
        WoB[i] = (_Float16)Wo[((size_t)l * EE + e) * EE + k];
    }
    if (i < LL * 65536) {
        int jj = i & 3, lane = (i >> 2) & 63, nt = (i >> 8) & 3,
            kt = (i >> 10) & 63, l = i >> 16;
        int e = nt * 32 + (lane & 31);
        int j = kt * 8 + (lane >> 5) * 4 + jj;
        W2B[i] = (_Float16)W2[((size_t)l * EE + e) * FF + j];
    }
}

__global__ __launch_bounds__(256, 2) void attn_kernel(
    const float* __restrict__ h, const float* __restrict__ theta8,
    float* __restrict__ o)
{
    __shared__ _Float16 encA[2][SS][4];
    __shared__ _Float16 encT[9][524];
    int blk = blockIdx.x;
    int bh = blk >> 2, qpart = blk & 3;
    int b = bh >> 4, hh = bh & 15;
    int tid = threadIdx.x;

    float4 tha = ((const float4*)theta8)[0];
    float4 thb = ((const float4*)theta8)[1];

#pragma unroll
    for (int kk = 0; kk < 2; kk++) {
        int k = tid + kk * 256;
        const float* hp = h + ((size_t)(b * SS + k) * EE + hh * 8);
        float oo[8];
        ring_from_x(*(const float4*)hp, *(const float4*)(hp + 4), tha, thb, oo);
        h4 lo = {(_Float16)oo[0], (_Float16)oo[1], (_Float16)oo[2], (_Float16)oo[3]};
        h4 hi = {(_Float16)oo[4], (_Float16)oo[5], (_Float16)oo[6], (_Float16)oo[7]};
        *(h4*)&encA[0][k][0] = lo;
        *(h4*)&encA[1][k][0] = hi;
#pragma unroll
        for (int d = 0; d < 8; d++) encT[d][k] = (_Float16)oo[d];
        encT[8][k] = (_Float16)1.0f;
    }
    __syncthreads();

    int lane = tid & 63, wv = tid >> 6;
    int col = lane & 31, hf = lane >> 5;
    int qtile = qpart * 128 + wv * 32;

    h4 bq = *(const h4*)&encA[hf][qtile + col][0];

    const float SC = 0.35355339059327373f * 1.4426950408889634f;
    f32x16 Oacc = {};
    for (int kt = 0; kt < SS; kt += 32) {
        h4 ak = *(const h4*)&encA[hf][kt + col][0];
        f32x16 Cz = {};
        f32x16 C = __builtin_amdgcn_mfma_f32_32x32x8f16(ak, bq, Cz, 0, 0, 0);
        h2 ph[8];
#pragma unroll
        for (int r = 0; r < 16; r += 2) {
            float x0 = C[r] * SC, x1 = C[r + 1] * SC;
            float w0, w1;
            asm("v_exp_f32 %0, %1" : "=v"(w0) : "v"(x0));
            asm("v_exp_f32 %0, %1" : "=v"(w1) : "v"(x1));
            ph[r >> 1] = (h2)__builtin_amdgcn_cvt_pkrtz(w0, w1);
        }
#pragma unroll
        for (int j = 0; j < 4; j++) {
            h4 ap = {ph[2 * j][0], ph[2 * j][1], ph[2 * j + 1][0], ph[2 * j + 1][1]};
            h4 bv = {};
            if (col <= 8)
                bv = *(const h4*)&encT[col][kt + 8 * j + 4 * hf];
            Oacc = __builtin_amdgcn_mfma_f32_32x32x8f16(ap, bv, Oacc, 0, 0, 0);
        }
    }

#pragma unroll
    for (int r = 0; r < 16; r++) {
        float rs  = __shfl(Oacc[r], 8, 32);
        float inv = __builtin_amdgcn_rcpf(rs);
        if (col < 8) {
            int q = qtile + (r & 3) + 8 * (r >> 2) + 4 * hf;
            o[((size_t)(b * SS + q)) * EE + hh * 8 + col] = Oacc[r] * inv;
        }
    }
}

__global__ __launch_bounds__(512, 2) void fused_kernel(
    float* __restrict__ h, const float* __restrict__ o,
    const _Float16* __restrict__ WoB, const _Float16* __restrict__ W2B,
    const float* __restrict__ W1, const float* __restrict__ ffn_theta,
    const float* __restrict__ ln1g, const float* __restrict__ ln1b,
    const float* __restrict__ ln2g, const float* __restrict__ ln2b)
{
    __shared__ _Float16 oA[32][132];
    __shared__ _Float16 hid16[32][516];
    __shared__ float vL[16][128];
    __shared__ float hL[16][128];
    __shared__ __align__(16) float measL[16][4];
    __shared__ float meanL[16], rstdL[16];

    int tid = threadIdx.x;
    int t0  = blockIdx.x * 16;

    {
        int t = tid >> 5, c4 = tid & 31;
        float4 ov = ((const float4*)o)[(size_t)(t0 + t) * 32 + c4];
        h4 hv = {(_Float16)ov.x, (_Float16)ov.y, (_Float16)ov.z, (_Float16)ov.w};
        *(h4*)&oA[t][c4 * 4] = hv;
        float4 hvf = ((const float4*)h)[(size_t)(t0 + t) * 32 + c4];
        *(float4*)&hL[t][c4 * 4] = hvf;
    }
    __syncthreads();

    int lane = tid & 63, wv = tid >> 6;
    int arow = lane & 31, hf = lane >> 5;
    int col  = lane & 31;
    int nt = wv & 3, kh = wv >> 2;

    f32x16 Cw = {};
    for (int kt = kh * 8; kt < kh * 8 + 8; kt++) {
        h4 a = *(const h4*)&oA[arow][kt * 8 + hf * 4];
        h4 bfrag = *(const h4*)&WoB[((size_t)(kt * 4 + nt) * 64 + lane) * 4];
        Cw = __builtin_amdgcn_mfma_f32_32x32x8f16(a, bfrag, Cw, 0, 0, 0);
    }
    if (kh == 0) {
#pragma unroll
        for (int r = 0; r < 8; r++)
            vL[(r & 3) + 8 * (r >> 2) + 4 * hf][nt * 32 + col] = Cw[r];
    }
    __syncthreads();
    if (kh == 1) {
#pragma unroll
        for (int r = 0; r < 8; r++)
            vL[(r & 3) + 8 * (r >> 2) + 4 * hf][nt * 32 + col] += Cw[r];
    }
    __syncthreads();

    int tt = tid >> 5, l32 = tid & 31;
    {
        float sm = 0.f, sq = 0.f;
#pragma unroll
        for (int i = 0; i < 4; i++) {
            float x = vL[tt][l32 + 32 * i] + hL[tt][l32 + 32 * i];
            sm += x; sq += x * x;
        }
#pragma unroll
        for (int ofs = 16; ofs >= 1; ofs >>= 1) {
            sm += __shfl_xor(sm, ofs);
            sq += __shfl_xor(sq, ofs);
        }
        if (l32 == 0) {
            float mu = sm * (1.f / 128.f);
            meanL[tt] = mu;
            rstdL[tt] = rsqrtf(sq * (1.f / 128.f) - mu * mu + 1e-5f);
        }
    }
    __syncthreads();

    int e = tid & 127, g = tid >> 7;
    float ge1 = ln1g[e], be1 = ln1b[e];
    float h1[4];
#pragma unroll
    for (int t = 0; t < 4; t++) {
        int idx = g * 4 + t;
        float v = vL[idx][e] + hL[idx][e];
        h1[t] = (v - meanL[idx]) * rstdL[idx] * ge1 + be1;
    }
    if (e < 4) {
        float cth = cosf(ffn_theta[e]);
#pragma unroll
        for (int t = 0; t < 4; t++) measL[g * 4 + t][e] = cosf(h1[t]) * cth;
    }
    __syncthreads();

    {
        float4 w1v = ((const float4*)W1)[tid];
#pragma unroll
        for (int t = 0; t < 16; t++) {
            float4 mv = *(const float4*)&measL[t][0];
            float hv = mv.x * w1v.x + mv.y * w1v.y + mv.z * w1v.z + mv.w * w1v.w;
            hid16[t][tid] = (_Float16)fmaxf(hv, 0.f);
        }
    }
    __syncthreads();

    f32x16 Cf = {};
    for (int kt = kh * 32; kt < kh * 32 + 32; kt++) {
        h4 a = *(const h4*)&hid16[arow][kt * 8 + hf * 4];
        h4 bfrag = *(const h4*)&W2B[((size_t)(kt * 4 + nt) * 64 + lane) * 4];
        Cf = __builtin_amdgcn_mfma_f32_32x32x8f16(a, bfrag, Cf, 0, 0, 0);
    }
    if (kh == 0) {
#pragma unroll
        for (int r = 0; r < 8; r++)
            vL[(r & 3) + 8 * (r >> 2) + 4 * hf][nt * 32 + col] = Cf[r];
    }
    __syncthreads();
    if (kh == 1) {
#pragma unroll
        for (int r = 0; r < 8; r++)
            vL[(r & 3) + 8 * (r >> 2) + 4 * hf][nt * 32 + col] += Cf[r];
    }
    __syncthreads();

    float v2[4];
#pragma unroll
    for (int t = 0; t < 4; t++) {
        int idx = g * 4 + t;
        v2[t] = h1[t] + vL[idx][e];
        hL[idx][e] = v2[t];
    }
    __syncthreads();
    {
        float sm = 0.f, sq = 0.f;
#pragma unroll
        for (int i = 0; i < 4; i++) {
            float x = hL[tt][l32 + 32 * i];
            sm += x; sq += x * x;
        }
#pragma unroll
        for (int ofs = 16; ofs >= 1; ofs >>= 1) {
            sm += __shfl_xor(sm, ofs);
            sq += __shfl_xor(sq, ofs);
        }
        if (l32 == 0) {
            float mu = sm * (1.f / 128.f);
            meanL[tt] = mu;
            rstdL[tt] = rsqrtf(sq * (1.f / 128.f) - mu * mu + 1e-5f);
        }
    }
    __syncthreads();
    float ge2 = ln2g[e], be2 = ln2b[e];
#pragma unroll
    for (int t = 0; t < 4; t++) {
        int idx = g * 4 + t;
        h[(size_t)(t0 + idx) * 128 + e] = (v2[t] - meanL[idx]) * rstdL[idx] * ge2 + be2;
    }
}

__global__ __launch_bounds__(256) void head_kernel(
    const float* __restrict__ h, const float* __restrict__ Wc,
    const float* __restrict__ bc, float* __restrict__ out)
{
    __shared__ float4 red[8][32];
    __shared__ float pooled[EE];
    int b = blockIdx.x, tid = threadIdx.x;
    int eq = tid & 31, sg = tid >> 5;
    const float4* h4p = (const float4*)h + (size_t)b * SS * 32;
    float4 acc = make_float4(0, 0, 0, 0);
    for (int r = 0; r < 64; r++) {
        int s = r * 8 + sg;
        float4 x = h4p[(size_t)s * 32 + eq];
        acc.x += x.x; acc.y += x.y; acc.z += x.z; acc.w += x.w;
    }
    red[sg][eq] = acc;
    __syncthreads();
    if (sg == 0) {
        float4 a = red[0][eq];
#pragma unroll
        for (int i = 1; i < 8; i++) {
            float4 x = red[i][eq];
            a.x += x.x; a.y += x.y; a.z += x.z; a.w += x.w;
        }
        const float s = 1.f / (float)SS;
        *(float4*)&pooled[eq * 4] = make_float4(a.x * s, a.y * s, a.z * s, a.w * s);
    }
    __syncthreads();
    if (tid < 160) {
        int c = tid >> 4, l16 = tid & 15;
        float p = 0.f;
#pragma unroll
        for (int i = 0; i < 8; i++) {
            int k = l16 + i * 16;
            p += pooled[k] * Wc[(size_t)c * EE + k];
        }
#pragma unroll
        for (int ofs = 8; ofs >= 1; ofs >>= 1) p += __shfl_xor(p, ofs);
        if (l16 == 0) out[b * CC + c] = p + bc[c];
    }
}

// ---------------------------------------------------------------------------
extern "C" void kernel_launch(void* const* d_in, const int* in_sizes, int n_in,
                              void* d_out, int out_size, void* d_ws, size_t ws_size,
                              hipStream_t stream)
{
    const int*   tokens     = (const int*)d_in[0];
    const float* emb        = (const float*)d_in[1];
    const float* attn_theta = (const float*)d_in[2];
    const float* ffn_theta  = (const float*)d_in[3];
    const float* Wo         = (const float*)d_in[4];
    const float* W1         = (const float*)d_in[5];
    const float* W2         = (const float*)d_in[6];
    const float* ln1g       = (const float*)d_in[7];
    const float* ln1b       = (const float*)d_in[8];
    const float* ln2g       = (const float*)d_in[9];
    const float* ln2b       = (const float*)d_in[10];
    const float* Wc         = (const float*)d_in[11];
    const float* bc         = (const float*)d_in[12];
    float* out = (float*)d_out;

    float* ws  = (float*)d_ws;
    float* h   = ws;                               // 524288 floats
    float* o   = ws + 524288;                      // 524288 floats
    _Float16* WoB = (_Float16*)(ws + 1048576);     // 65536 halves
    _Float16* W2B = (_Float16*)(ws + 1081344);     // 262144 halves

    void* args[] = {
        (void*)&tokens, (void*)&emb, (void*)&attn_theta, (void*)&ffn_theta,
        (void*)&Wo, (void*)&W1, (void*)&W2,
        (void*)&ln1g, (void*)&ln1b, (void*)&ln2g, (void*)&ln2b,
        (void*)&Wc, (void*)&bc, (void*)&out,
        (void*)&h, (void*)&o, (void*)&WoB, (void*)&W2B
    };
    hipError_t ce = hipLaunchCooperativeKernel((void*)mega_kernel, dim3(256),
                                               dim3(256), args, 0, stream);
    if (ce == hipSuccess) return;

    // -------- fallback: proven round-6 multi-kernel pipeline --------
    prep_kernel<<<dim3(2048), dim3(256), 0, stream>>>(tokens, emb, Wo, W2, h, WoB, W2B);
    for (int l = 0; l < LL; l++) {
        attn_kernel<<<dim3(512), dim3(256), 0, stream>>>(
            h, attn_theta + (size_t)l * 8, o);
        fused_kernel<<<dim3(256), dim3(512), 0, stream>>>(
            h, o,
            WoB + (size_t)l * 16384,
            W2B + (size_t)l * 65536,
            W1 + (size_t)l * 2048,
            ffn_theta + (size_t)l * 4,
            ln1g + (size_t)l * EE, ln1b + (size_t)l * EE,
            ln2g + (size_t)l * EE, ln2b + (size_t)l * EE);
    }
    head_kernel<<<dim3(BB), dim3(256), 0, stream>>>(h, Wc, bc, out);
}

// Round 9
// 108.480 us; speedup vs baseline: 3.9761x; 3.9761x over previous
//
#include <hip/hip_runtime.h>
#include <math.h>

// Problem dims
#define BB  8
#define SS  512
#define EE  128
#define HH  16
#define LL  4
#define FF  512
#define CC  10

typedef _Float16 h2 __attribute__((ext_vector_type(2)));
typedef _Float16 h4 __attribute__((ext_vector_type(4)));
typedef float f32x16 __attribute__((ext_vector_type(16)));

// ---------------------------------------------------------------------------
// fast cos: cos(x) = v_cos(fract(x / 2pi))  (v_cos takes revolutions)
// ---------------------------------------------------------------------------
__device__ __forceinline__ float fastcos(float x)
{
    float r = x * 0.15915494309189535f;
    asm("v_fract_f32 %0, %1" : "=v"(r) : "v"(r));
    float c;
    asm("v_cos_f32 %0, %1" : "=v"(c) : "v"(r));
    return c;
}

// ---------------------------------------------------------------------------
// prep: embed + f16 B-fragment swizzles for the fused MFMA GEMMs.
// WoB[l][kt(16)][nt(4)][lane(64)][jj(4)] = Wo[l][e][k], e=nt*32+(lane&31),
//      k=kt*8+(lane>>5)*4+jj
// W2B[l][kt(64)][nt(4)][lane(64)][jj(4)] = W2[l][e][j]
// ---------------------------------------------------------------------------
__global__ __launch_bounds__(256) void prep_kernel(
    const int* __restrict__ tokens, const float* __restrict__ emb,
    const float* __restrict__ Wo, const float* __restrict__ W2,
    float* __restrict__ h, _Float16* __restrict__ WoB, _Float16* __restrict__ W2B)
{
    int i = blockIdx.x * 256 + threadIdx.x;
    {
        int e  = i & 127;
        int bs = i >> 7;
        int s  = bs & 511;
        int tok = tokens[bs];
        int half = e >> 1;
        float ang = (float)s * expf(-0.07195578415606394f * (float)(2 * half));
        float pe  = (e & 1) ? cosf(ang) : sinf(ang);
        h[i] = emb[(size_t)tok * EE + e] + pe;
    }
    if (i < LL * 16384) {
        int jj = i & 3, lane = (i >> 2) & 63, nt = (i >> 8) & 3,
            kt = (i >> 10) & 15, l = i >> 14;
        int e = nt * 32 + (lane & 31);
        int k = kt * 8 + (lane >> 5) * 4 + jj;
        WoB[i] = (_Float16)Wo[((size_t)l * EE + e) * EE + k];
    }
    if (i < LL * 65536) {
        int jj = i & 3, lane = (i >> 2) & 63, nt = (i >> 8) & 3,
            kt = (i >> 10) & 63, l = i >> 16;
        int e = nt * 32 + (lane & 31);
        int j = kt * 8 + (lane >> 5) * 4 + jj;
        W2B[i] = (_Float16)W2[((size_t)l * EE + e) * FF + j];
    }
}

// ---------------------------------------------------------------------------
// ring measurement from raw x, fast-cos version
// ---------------------------------------------------------------------------
__device__ __forceinline__ void ring_from_x_fast(
    const float4 xa, const float4 xb, const float4 tha, const float4 thb,
    float* o)
{
    float c0 = fastcos(xa.x + tha.x), c1 = fastcos(xa.y + tha.y),
          c2 = fastcos(xa.z + tha.z), c3 = fastcos(xa.w + tha.w),
          c4 = fastcos(xb.x + thb.x), c5 = fastcos(xb.y + thb.y),
          c6 = fastcos(xb.z + thb.z), c7 = fastcos(xb.w + thb.w);
    o[0] = c1 * c2 * c3 * c4 * c5 * c6 * c7;   // z0 (no c0)
    float cum = c0;
    cum *= c1; o[1] = cum;  cum *= c2; o[2] = cum;
    cum *= c3; o[3] = cum;  cum *= c4; o[4] = cum;
    cum *= c5; o[5] = cum;  cum *= c6; o[6] = cum;
    cum *= c7; o[7] = cum;
}

// ---------------------------------------------------------------------------
// MFMA attention (r5/r6-validated math; staging = fast-cos + packed writes).
// grid = 128 bh x 4 qparts = 512 blocks, 256 thr (4 waves).
// Per 32-key tile: S^T = mfma_32x32x8_f16(enc_k, enc_q); w = exp2(C*SC)
// (single-pass, |C*SC|<=4.08); packed f16 w-regs == PV A-operand exactly;
// V aug col 8 = ones -> rowsum free.
// ---------------------------------------------------------------------------
__global__ __launch_bounds__(256, 2) void attn_kernel(
    const float* __restrict__ h, const float* __restrict__ theta8,
    float* __restrict__ o)
{
    __shared__ _Float16 encA[2][SS][4];      // 8 KB
    __shared__ _Float16 encT[9][524];        // 9.2 KB
    int blk = blockIdx.x;
    int bh = blk >> 2, qpart = blk & 3;
    int b = bh >> 4, hh = bh & 15;
    int tid = threadIdx.x;

    float4 tha = ((const float4*)theta8)[0];
    float4 thb = ((const float4*)theta8)[1];

    // stage 512 keys: thread owns adjacent keys 2*tid, 2*tid+1
    {
        int k0 = 2 * tid;
        const float* hp0 = h + ((size_t)(b * SS + k0) * EE + hh * 8);
        const float* hp1 = hp0 + EE;
        float o0[8], o1[8];
        ring_from_x_fast(*(const float4*)hp0, *(const float4*)(hp0 + 4), tha, thb, o0);
        ring_from_x_fast(*(const float4*)hp1, *(const float4*)(hp1 + 4), tha, thb, o1);
        h4 lo0 = {(_Float16)o0[0], (_Float16)o0[1], (_Float16)o0[2], (_Float16)o0[3]};
        h4 hi0 = {(_Float16)o0[4], (_Float16)o0[5], (_Float16)o0[6], (_Float16)o0[7]};
        h4 lo1 = {(_Float16)o1[0], (_Float16)o1[1], (_Float16)o1[2], (_Float16)o1[3]};
        h4 hi1 = {(_Float16)o1[4], (_Float16)o1[5], (_Float16)o1[6], (_Float16)o1[7]};
        *(h4*)&encA[0][k0][0]     = lo0;
        *(h4*)&encA[0][k0 + 1][0] = lo1;
        *(h4*)&encA[1][k0][0]     = hi0;
        *(h4*)&encA[1][k0 + 1][0] = hi1;
#pragma unroll
        for (int d = 0; d < 8; d++) {
            h2 pr = {(_Float16)o0[d], (_Float16)o1[d]};
            *(h2*)&encT[d][k0] = pr;
        }
        h2 one2 = {(_Float16)1.0f, (_Float16)1.0f};
        *(h2*)&encT[8][k0] = one2;
    }
    __syncthreads();

    int lane = tid & 63, wv = tid >> 6;
    int col = lane & 31, hf = lane >> 5;
    int qtile = qpart * 128 + wv * 32;

    h4 bq = *(const h4*)&encA[hf][qtile + col][0];

    const float SC = 0.35355339059327373f * 1.4426950408889634f; // 1/sqrt(8)*log2e
    f32x16 Oacc = {};
    for (int kt = 0; kt < SS; kt += 32) {
        h4 ak = *(const h4*)&encA[hf][kt + col][0];
        f32x16 Cz = {};
        f32x16 C = __builtin_amdgcn_mfma_f32_32x32x8f16(ak, bq, Cz, 0, 0, 0);
        h2 ph[8];
#pragma unroll
        for (int r = 0; r < 16; r += 2) {
            float x0 = C[r] * SC, x1 = C[r + 1] * SC;
            float w0, w1;
            asm("v_exp_f32 %0, %1" : "=v"(w0) : "v"(x0));
            asm("v_exp_f32 %0, %1" : "=v"(w1) : "v"(x1));
            ph[r >> 1] = (h2)__builtin_amdgcn_cvt_pkrtz(w0, w1);
        }
#pragma unroll
        for (int j = 0; j < 4; j++) {
            h4 ap = {ph[2 * j][0], ph[2 * j][1], ph[2 * j + 1][0], ph[2 * j + 1][1]};
            h4 bv = {};
            if (col <= 8)
                bv = *(const h4*)&encT[col][kt + 8 * j + 4 * hf];
            Oacc = __builtin_amdgcn_mfma_f32_32x32x8f16(ap, bv, Oacc, 0, 0, 0);
        }
    }

#pragma unroll
    for (int r = 0; r < 16; r++) {
        float rs  = __shfl(Oacc[r], 8, 32);
        float inv = __builtin_amdgcn_rcpf(rs);
        if (col < 8) {
            int q = qtile + (r & 3) + 8 * (r >> 2) + 4 * hf;
            o[((size_t)(b * SS + q)) * EE + hh * 8 + col] = Oacc[r] * inv;
        }
    }
}

// ---------------------------------------------------------------------------
// Fused v5: 8 tokens/block, 256 threads (4 waves), grid 512 -> 2 blocks/CU.
// Wave = nt (32-col e-tile); full K per wave with dual accumulators
// (even/odd kt) for MFMA ILP. MFMA A rows 8-31 are junk (uninit LDS);
// junk is confined to C rows 8-31 which are never stored (only r<4 kept).
// LN/meas scaffolding = round-5-validated 8-token dataflow.
// ---------------------------------------------------------------------------
__global__ __launch_bounds__(256, 2) void fused_kernel(
    float* __restrict__ h, const float* __restrict__ o,
    const _Float16* __restrict__ WoB, const _Float16* __restrict__ W2B,
    const float* __restrict__ W1, const float* __restrict__ ffn_theta,
    const float* __restrict__ ln1g, const float* __restrict__ ln1b,
    const float* __restrict__ ln2g, const float* __restrict__ ln2b)
{
    __shared__ _Float16 oA[32][132];        // rows 0-7 real
    __shared__ _Float16 hid16[32][516];     // rows 0-7 real
    __shared__ float vL[8][128];
    __shared__ float hL[8][128];
    __shared__ __align__(16) float measL[8][4];
    __shared__ float meanL[8], rstdL[8];

    int tid = threadIdx.x;
    int t0  = blockIdx.x * 8;

    // stage o (f32->f16 A layout) + h residual: 8 rows x 32 quads = 256 thr
    {
        int t = tid >> 5, c4 = tid & 31;
        float4 ov = ((const float4*)o)[(size_t)(t0 + t) * 32 + c4];
        h4 hv = {(_Float16)ov.x, (_Float16)ov.y, (_Float16)ov.z, (_Float16)ov.w};
        *(h4*)&oA[t][c4 * 4] = hv;
        float4 hvf = ((const float4*)h)[(size_t)(t0 + t) * 32 + c4];
        *(float4*)&hL[t][c4 * 4] = hvf;
    }
    __syncthreads();

    int lane = tid & 63, wv = tid >> 6;
    int arow = lane & 31, hf = lane >> 5;
    int col  = lane & 31;
    int nt = wv;

    // ---- Wo GEMM: K=128 (16 kt), dual accumulators ----
    f32x16 Ca = {}, Cb = {};
    for (int kt = 0; kt < 16; kt += 2) {
        h4 a0 = *(const h4*)&oA[arow][kt * 8 + hf * 4];
        h4 b0 = *(const h4*)&WoB[((size_t)((kt * 4 + nt) * 64 + lane)) * 4];
        Ca = __builtin_amdgcn_mfma_f32_32x32x8f16(a0, b0, Ca, 0, 0, 0);
        h4 a1 = *(const h4*)&oA[arow][(kt + 1) * 8 + hf * 4];
        h4 b1 = *(const h4*)&WoB[((size_t)(((kt + 1) * 4 + nt) * 64 + lane)) * 4];
        Cb = __builtin_amdgcn_mfma_f32_32x32x8f16(a1, b1, Cb, 0, 0, 0);
    }
#pragma unroll
    for (int r = 0; r < 4; r++)
        vL[r + 4 * hf][nt * 32 + col] = Ca[r] + Cb[r];
    __syncthreads();

    // ---- LN1 stats: 32 lanes/token ----
    int tt = tid >> 5, l32 = tid & 31;
    {
        float sm = 0.f, sq = 0.f;
#pragma unroll
        for (int i = 0; i < 4; i++) {
            float x = vL[tt][l32 + 32 * i] + hL[tt][l32 + 32 * i];
            sm += x; sq += x * x;
        }
#pragma unroll
        for (int ofs = 16; ofs >= 1; ofs >>= 1) {
            sm += __shfl_xor(sm, ofs);
            sq += __shfl_xor(sq, ofs);
        }
        if (l32 == 0) {
            float mu = sm * (1.f / 128.f);
            meanL[tt] = mu;
            rstdL[tt] = rsqrtf(sq * (1.f / 128.f) - mu * mu + 1e-5f);
        }
    }
    __syncthreads();

    // ---- h1 (regs) + meas ----
    int e = tid & 127, g = tid >> 7;         // g in {0,1}, 4 tokens each
    float ge1 = ln1g[e], be1 = ln1b[e];
    float h1[4];
#pragma unroll
    for (int t = 0; t < 4; t++) {
        int idx = g * 4 + t;
        float v = vL[idx][e] + hL[idx][e];
        h1[t] = (v - meanL[idx]) * rstdL[idx] * ge1 + be1;
    }
    if (e < 4) {
        float cth = cosf(ffn_theta[e]);
#pragma unroll
        for (int t = 0; t < 4; t++) measL[g * 4 + t][e] = cosf(h1[t]) * cth;
    }
    __syncthreads();

    // ---- hidden = relu(meas @ W1^T) -> f16 A layout; j = tid, tid+256 ----
#pragma unroll
    for (int jj = 0; jj < 2; jj++) {
        int j = jj * 256 + tid;
        float4 w1v = ((const float4*)W1)[j];
#pragma unroll
        for (int t = 0; t < 8; t++) {
            float4 mv = *(const float4*)&measL[t][0];
            float hv = mv.x * w1v.x + mv.y * w1v.y + mv.z * w1v.z + mv.w * w1v.w;
            hid16[t][j] = (_Float16)fmaxf(hv, 0.f);
        }
    }
    __syncthreads();

    // ---- W2 GEMM: K=512 (64 kt), dual accumulators ----
    f32x16 Fa = {}, Fb = {};
    for (int kt = 0; kt < 64; kt += 2) {
        h4 a0 = *(const h4*)&hid16[arow][kt * 8 + hf * 4];
        h4 b0 = *(const h4*)&W2B[((size_t)((kt * 4 + nt) * 64 + lane)) * 4];
        Fa = __builtin_amdgcn_mfma_f32_32x32x8f16(a0, b0, Fa, 0, 0, 0);
        h4 a1 = *(const h4*)&hid16[arow][(kt + 1) * 8 + hf * 4];
        h4 b1 = *(const h4*)&W2B[((size_t)(((kt + 1) * 4 + nt) * 64 + lane)) * 4];
        Fb = __builtin_amdgcn_mfma_f32_32x32x8f16(a1, b1, Fb, 0, 0, 0);
    }
#pragma unroll
    for (int r = 0; r < 4; r++)
        vL[r + 4 * hf][nt * 32 + col] = Fa[r] + Fb[r];
    __syncthreads();

    // ---- v2 = h1 + f -> hL; LN2; write h ----
    float v2[4];
#pragma unroll
    for (int t = 0; t < 4; t++) {
        int idx = g * 4 + t;
        v2[t] = h1[t] + vL[idx][e];
        hL[idx][e] = v2[t];
    }
    __syncthreads();
    {
        float sm = 0.f, sq = 0.f;
#pragma unroll
        for (int i = 0; i < 4; i++) {
            float x = hL[tt][l32 + 32 * i];
            sm += x; sq += x * x;
        }
#pragma unroll
        for (int ofs = 16; ofs >= 1; ofs >>= 1) {
            sm += __shfl_xor(sm, ofs);
            sq += __shfl_xor(sq, ofs);
        }
        if (l32 == 0) {
            float mu = sm * (1.f / 128.f);
            meanL[tt] = mu;
            rstdL[tt] = rsqrtf(sq * (1.f / 128.f) - mu * mu + 1e-5f);
        }
    }
    __syncthreads();
    float ge2 = ln2g[e], be2 = ln2b[e];
#pragma unroll
    for (int t = 0; t < 4; t++) {
        int idx = g * 4 + t;
        h[(size_t)(t0 + idx) * 128 + e] = (v2[t] - meanL[idx]) * rstdL[idx] * ge2 + be2;
    }
}

// ---------------------------------------------------------------------------
// pooled = mean_s h; out = pooled @ Wc^T + bc.  8 blocks x 256 threads.
// ---------------------------------------------------------------------------
__global__ __launch_bounds__(256) void head_kernel(
    const float* __restrict__ h, const float* __restrict__ Wc,
    const float* __restrict__ bc, float* __restrict__ out)
{
    __shared__ float4 red[8][32];
    __shared__ float pooled[EE];
    int b = blockIdx.x, tid = threadIdx.x;
    int eq = tid & 31, sg = tid >> 5;
    const float4* h4p = (const float4*)h + (size_t)b * SS * 32;
    float4 acc = make_float4(0, 0, 0, 0);
    for (int r = 0; r < 64; r++) {
        int s = r * 8 + sg;
        float4 x = h4p[(size_t)s * 32 + eq];
        acc.x += x.x; acc.y += x.y; acc.z += x.z; acc.w += x.w;
    }
    red[sg][eq] = acc;
    __syncthreads();
    if (sg == 0) {
        float4 a = red[0][eq];
#pragma unroll
        for (int i = 1; i < 8; i++) {
            float4 x = red[i][eq];
            a.x += x.x; a.y += x.y; a.z += x.z; a.w += x.w;
        }
        const float s = 1.f / (float)SS;
        *(float4*)&pooled[eq * 4] = make_float4(a.x * s, a.y * s, a.z * s, a.w * s);
    }
    __syncthreads();
    if (tid < 160) {
        int c = tid >> 4, l16 = tid & 15;
        float p = 0.f;
#pragma unroll
        for (int i = 0; i < 8; i++) {
            int k = l16 + i * 16;
            p += pooled[k] * Wc[(size_t)c * EE + k];
        }
#pragma unroll
        for (int ofs = 8; ofs >= 1; ofs >>= 1) p += __shfl_xor(p, ofs);
        if (l16 == 0) out[b * CC + c] = p + bc[c];
    }
}

// ---------------------------------------------------------------------------
extern "C" void kernel_launch(void* const* d_in, const int* in_sizes, int n_in,
                              void* d_out, int out_size, void* d_ws, size_t ws_size,
                              hipStream_t stream)
{
    const int*   tokens     = (const int*)d_in[0];
    const float* emb        = (const float*)d_in[1];
    const float* attn_theta = (const float*)d_in[2];
    const float* ffn_theta  = (const float*)d_in[3];
    const float* Wo         = (const float*)d_in[4];
    const float* W1         = (const float*)d_in[5];
    const float* W2         = (const float*)d_in[6];
    const float* ln1g       = (const float*)d_in[7];
    const float* ln1b       = (const float*)d_in[8];
    const float* ln2g       = (const float*)d_in[9];
    const float* ln2b       = (const float*)d_in[10];
    const float* Wc         = (const float*)d_in[11];
    const float* bc         = (const float*)d_in[12];
    float* out = (float*)d_out;

    float* ws  = (float*)d_ws;
    float* h   = ws;                               // 524288 floats
    float* o   = ws + 524288;                      // 524288 floats
    _Float16* WoB = (_Float16*)(ws + 1048576);     // 65536 halves
    _Float16* W2B = (_Float16*)(ws + 1081344);     // 262144 halves

    prep_kernel<<<dim3(2048), dim3(256), 0, stream>>>(tokens, emb, Wo, W2, h, WoB, W2B);

    for (int l = 0; l < LL; l++) {
        attn_kernel<<<dim3(512), dim3(256), 0, stream>>>(
            h, attn_theta + (size_t)l * 8, o);
        fused_kernel<<<dim3(512), dim3(256), 0, stream>>>(
            h, o,
            WoB + (size_t)l * 16384,
            W2B + (size_t)l * 65536,
            W1 + (size_t)l * 2048,
            ffn_theta + (size_t)l * 4,
            ln1g + (size_t)l * EE, ln1b + (size_t)l * EE,
            ln2g + (size_t)l * EE, ln2b + (size_t)l * EE);
    }

    head_kernel<<<dim3(BB), dim3(256), 0, stream>>>(h, Wc, bc, out);
}

// Round 10
// 102.421 us; speedup vs baseline: 4.2113x; 1.0592x over previous
//
#include <hip/hip_runtime.h>
#include <math.h>

// Problem dims
#define BB  8
#define SS  512
#define EE  128
#define HH  16
#define LL  4
#define FF  512
#define CC  10

typedef _Float16 h2 __attribute__((ext_vector_type(2)));
typedef _Float16 h4 __attribute__((ext_vector_type(4)));
typedef float f32x16 __attribute__((ext_vector_type(16)));

// ---------------------------------------------------------------------------
// fast cos: cos(x) = v_cos(fract(x / 2pi))  (v_cos takes revolutions)
// ---------------------------------------------------------------------------
__device__ __forceinline__ float fastcos(float x)
{
    float r = x * 0.15915494309189535f;
    asm("v_fract_f32 %0, %1" : "=v"(r) : "v"(r));
    float c;
    asm("v_cos_f32 %0, %1" : "=v"(c) : "v"(r));
    return c;
}

// ---------------------------------------------------------------------------
// prep: embed + f16 B-fragment swizzles for the fused MFMA GEMMs.
// WoB[l][kt(16)][nt(4)][lane(64)][jj(4)] = Wo[l][e][k], e=nt*32+(lane&31),
//      k=kt*8+(lane>>5)*4+jj
// W2B[l][kt(64)][nt(4)][lane(64)][jj(4)] = W2[l][e][j]
// ---------------------------------------------------------------------------
__global__ __launch_bounds__(256) void prep_kernel(
    const int* __restrict__ tokens, const float* __restrict__ emb,
    const float* __restrict__ Wo, const float* __restrict__ W2,
    float* __restrict__ h, _Float16* __restrict__ WoB, _Float16* __restrict__ W2B)
{
    int i = blockIdx.x * 256 + threadIdx.x;
    {
        int e  = i & 127;
        int bs = i >> 7;
        int s  = bs & 511;
        int tok = tokens[bs];
        int half = e >> 1;
        float ang = (float)s * expf(-0.07195578415606394f * (float)(2 * half));
        float pe  = (e & 1) ? cosf(ang) : sinf(ang);
        h[i] = emb[(size_t)tok * EE + e] + pe;
    }
    if (i < LL * 16384) {
        int jj = i & 3, lane = (i >> 2) & 63, nt = (i >> 8) & 3,
            kt = (i >> 10) & 15, l = i >> 14;
        int e = nt * 32 + (lane & 31);
        int k = kt * 8 + (lane >> 5) * 4 + jj;
        WoB[i] = (_Float16)Wo[((size_t)l * EE + e) * EE + k];
    }
    if (i < LL * 65536) {
        int jj = i & 3, lane = (i >> 2) & 63, nt = (i >> 8) & 3,
            kt = (i >> 10) & 63, l = i >> 16;
        int e = nt * 32 + (lane & 31);
        int j = kt * 8 + (lane >> 5) * 4 + jj;
        W2B[i] = (_Float16)W2[((size_t)l * EE + e) * FF + j];
    }
}

// ---------------------------------------------------------------------------
// ring measurement from raw x, fast-cos version
// ---------------------------------------------------------------------------
__device__ __forceinline__ void ring_from_x_fast(
    const float4 xa, const float4 xb, const float4 tha, const float4 thb,
    float* o)
{
    float c0 = fastcos(xa.x + tha.x), c1 = fastcos(xa.y + tha.y),
          c2 = fastcos(xa.z + tha.z), c3 = fastcos(xa.w + tha.w),
          c4 = fastcos(xb.x + thb.x), c5 = fastcos(xb.y + thb.y),
          c6 = fastcos(xb.z + thb.z), c7 = fastcos(xb.w + thb.w);
    o[0] = c1 * c2 * c3 * c4 * c5 * c6 * c7;   // z0 (no c0)
    float cum = c0;
    cum *= c1; o[1] = cum;  cum *= c2; o[2] = cum;
    cum *= c3; o[3] = cum;  cum *= c4; o[4] = cum;
    cum *= c5; o[5] = cum;  cum *= c6; o[6] = cum;
    cum *= c7; o[7] = cum;
}

// ---------------------------------------------------------------------------
// MFMA attention, key-split-2. grid = 128 bh x 4 qparts x 2 khalf = 1024
// blocks, 256 thr (4 waves) -> 4 blocks/CU. Each block: 256 keys.
// Writes UNNORMALIZED partial PV accumulation aP (B,S,E) and partial
// rowsum sP (B,S,H) — V-aug ones column (col 8) delivers the rowsum in
// the same PV MFMAs; lane col==8 holds it directly.
// Queries' enc recomputed in-register (not staged).
// Math per tile = r5/r6-validated: S^T mfma -> exp2 -> packed f16 == PV A.
// ---------------------------------------------------------------------------
__global__ __launch_bounds__(256, 4) void attn_kernel(
    const float* __restrict__ h, const float* __restrict__ theta8,
    float* __restrict__ a1, float* __restrict__ a2,
    float* __restrict__ s1, float* __restrict__ s2)
{
    __shared__ _Float16 encA[2][256][4];     // 4 KB
    __shared__ _Float16 encT[9][260];        // 4.6 KB, row stride 2 banks
    int blk = blockIdx.x;
    int bh = blk >> 3, qpart = (blk >> 1) & 3, kh = blk & 1;
    int b = bh >> 4, hh = bh & 15;
    int tid = threadIdx.x;

    float4 tha = ((const float4*)theta8)[0];
    float4 thb = ((const float4*)theta8)[1];

    // stage this block's 256 keys (1 per thread)
    {
        int k = kh * 256 + tid;
        const float* hp = h + ((size_t)(b * SS + k) * EE + hh * 8);
        float oo[8];
        ring_from_x_fast(*(const float4*)hp, *(const float4*)(hp + 4), tha, thb, oo);
        h4 lo = {(_Float16)oo[0], (_Float16)oo[1], (_Float16)oo[2], (_Float16)oo[3]};
        h4 hi = {(_Float16)oo[4], (_Float16)oo[5], (_Float16)oo[6], (_Float16)oo[7]};
        *(h4*)&encA[0][tid][0] = lo;
        *(h4*)&encA[1][tid][0] = hi;
#pragma unroll
        for (int d = 0; d < 8; d++) encT[d][tid] = (_Float16)oo[d];
        encT[8][tid] = (_Float16)1.0f;
    }

    int lane = tid & 63, wv = tid >> 6;
    int col = lane & 31, hf = lane >> 5;
    int qtile = qpart * 128 + wv * 32;

    // own query enc in registers
    h4 bq;
    {
        const float* hp = h + ((size_t)(b * SS + qtile + col) * EE + hh * 8);
        float qq[8];
        ring_from_x_fast(*(const float4*)hp, *(const float4*)(hp + 4), tha, thb, qq);
        bq[0] = (_Float16)qq[4 * hf];
        bq[1] = (_Float16)qq[4 * hf + 1];
        bq[2] = (_Float16)qq[4 * hf + 2];
        bq[3] = (_Float16)qq[4 * hf + 3];
    }
    __syncthreads();

    const float SC = 0.35355339059327373f * 1.4426950408889634f; // 1/sqrt(8)*log2e
    f32x16 Oacc = {};
    for (int kt = 0; kt < 256; kt += 32) {
        h4 ak = *(const h4*)&encA[hf][kt + col][0];
        f32x16 Cz = {};
        f32x16 C = __builtin_amdgcn_mfma_f32_32x32x8f16(ak, bq, Cz, 0, 0, 0);
        h2 ph[8];
#pragma unroll
        for (int r = 0; r < 16; r += 2) {
            float x0 = C[r] * SC, x1 = C[r + 1] * SC;
            float w0, w1;
            asm("v_exp_f32 %0, %1" : "=v"(w0) : "v"(x0));
            asm("v_exp_f32 %0, %1" : "=v"(w1) : "v"(x1));
            ph[r >> 1] = (h2)__builtin_amdgcn_cvt_pkrtz(w0, w1);
        }
#pragma unroll
        for (int j = 0; j < 4; j++) {
            h4 ap = {ph[2 * j][0], ph[2 * j][1], ph[2 * j + 1][0], ph[2 * j + 1][1]};
            h4 bv = {};
            if (col <= 8)
                bv = *(const h4*)&encT[col][kt + 8 * j + 4 * hf];
            Oacc = __builtin_amdgcn_mfma_f32_32x32x8f16(ap, bv, Oacc, 0, 0, 0);
        }
    }

    // write unnormalized partials; lane col==8 has the partial rowsum
    float* aP = kh ? a2 : a1;
    float* sP = kh ? s2 : s1;
#pragma unroll
    for (int r = 0; r < 16; r++) {
        int q = qtile + (r & 3) + 8 * (r >> 2) + 4 * hf;
        if (col < 8)
            aP[((size_t)(b * SS + q)) * EE + hh * 8 + col] = Oacc[r];
        else if (col == 8)
            sP[((size_t)(b * SS + q)) * HH + hh] = Oacc[r];
    }
}

// ---------------------------------------------------------------------------
// Fused v6 = round-6-validated geometry (16 tokens/block, 512 thr, grid 256,
// kh-split K) + attention partial-combine in staging + dual-acc W2 loop.
// MFMA rows 16-31 junk -> confined to C rows 16-31, never stored.
// ---------------------------------------------------------------------------
__global__ __launch_bounds__(512, 2) void fused_kernel(
    float* __restrict__ h,
    const float* __restrict__ a1, const float* __restrict__ a2,
    const float* __restrict__ s1, const float* __restrict__ s2,
    const _Float16* __restrict__ WoB, const _Float16* __restrict__ W2B,
    const float* __restrict__ W1, const float* __restrict__ ffn_theta,
    const float* __restrict__ ln1g, const float* __restrict__ ln1b,
    const float* __restrict__ ln2g, const float* __restrict__ ln2b)
{
    __shared__ _Float16 oA[32][132];
    __shared__ _Float16 hid16[32][516];
    __shared__ float vL[16][128];
    __shared__ float hL[16][128];
    __shared__ __align__(16) float measL[16][4];
    __shared__ float meanL[16], rstdL[16];
    __shared__ float invL[16][16];

    int tid = threadIdx.x;
    int t0  = blockIdx.x * 16;

    // inv row-sums
    if (tid < 256) {
        int t = tid >> 4, hh = tid & 15;
        size_t idx = (size_t)(t0 + t) * HH + hh;
        invL[t][hh] = 1.0f / (s1[idx] + s2[idx]);
    }
    __syncthreads();

    // stage o = (a1+a2)*inv (f32->f16 A layout) + h residual
    {
        int t = tid >> 5, c4 = tid & 31;
        float inv = invL[t][c4 >> 1];
        float4 p1 = ((const float4*)a1)[(size_t)(t0 + t) * 32 + c4];
        float4 p2 = ((const float4*)a2)[(size_t)(t0 + t) * 32 + c4];
        h4 hv = {(_Float16)((p1.x + p2.x) * inv), (_Float16)((p1.y + p2.y) * inv),
                 (_Float16)((p1.z + p2.z) * inv), (_Float16)((p1.w + p2.w) * inv)};
        *(h4*)&oA[t][c4 * 4] = hv;
        float4 hvf = ((const float4*)h)[(size_t)(t0 + t) * 32 + c4];
        *(float4*)&hL[t][c4 * 4] = hvf;
    }
    __syncthreads();

    int lane = tid & 63, wv = tid >> 6;
    int arow = lane & 31, hf = lane >> 5;
    int col  = lane & 31;
    int nt = wv & 3, kh = wv >> 2;

    // ---- Wo GEMM: K=128, kh halves of 8 kt ----
    f32x16 Cw = {};
    for (int kt = kh * 8; kt < kh * 8 + 8; kt++) {
        h4 a = *(const h4*)&oA[arow][kt * 8 + hf * 4];
        h4 bfrag = *(const h4*)&WoB[((size_t)(kt * 4 + nt) * 64 + lane) * 4];
        Cw = __builtin_amdgcn_mfma_f32_32x32x8f16(a, bfrag, Cw, 0, 0, 0);
    }
    if (kh == 0) {
#pragma unroll
        for (int r = 0; r < 8; r++)
            vL[(r & 3) + 8 * (r >> 2) + 4 * hf][nt * 32 + col] = Cw[r];
    }
    __syncthreads();
    if (kh == 1) {
#pragma unroll
        for (int r = 0; r < 8; r++)
            vL[(r & 3) + 8 * (r >> 2) + 4 * hf][nt * 32 + col] += Cw[r];
    }
    __syncthreads();

    // ---- LN1 stats: 16 lanes/token ----
    int tt = tid >> 5, l32 = tid & 31;
    {
        float sm = 0.f, sq = 0.f;
#pragma unroll
        for (int i = 0; i < 4; i++) {
            float x = vL[tt][l32 + 32 * i] + hL[tt][l32 + 32 * i];
            sm += x; sq += x * x;
        }
#pragma unroll
        for (int ofs = 16; ofs >= 1; ofs >>= 1) {
            sm += __shfl_xor(sm, ofs);
            sq += __shfl_xor(sq, ofs);
        }
        if (l32 == 0) {
            float mu = sm * (1.f / 128.f);
            meanL[tt] = mu;
            rstdL[tt] = rsqrtf(sq * (1.f / 128.f) - mu * mu + 1e-5f);
        }
    }
    __syncthreads();

    int e = tid & 127, g = tid >> 7;
    float ge1 = ln1g[e], be1 = ln1b[e];
    float h1[4];
#pragma unroll
    for (int t = 0; t < 4; t++) {
        int idx = g * 4 + t;
        float v = vL[idx][e] + hL[idx][e];
        h1[t] = (v - meanL[idx]) * rstdL[idx] * ge1 + be1;
    }
    if (e < 4) {
        float cth = cosf(ffn_theta[e]);
#pragma unroll
        for (int t = 0; t < 4; t++) measL[g * 4 + t][e] = cosf(h1[t]) * cth;
    }
    __syncthreads();

    // ---- hidden = relu(meas @ W1^T) -> f16 A layout; thread owns j=tid ----
    {
        float4 w1v = ((const float4*)W1)[tid];
#pragma unroll
        for (int t = 0; t < 16; t++) {
            float4 mv = *(const float4*)&measL[t][0];
            float hv = mv.x * w1v.x + mv.y * w1v.y + mv.z * w1v.z + mv.w * w1v.w;
            hid16[t][tid] = (_Float16)fmaxf(hv, 0.f);
        }
    }
    __syncthreads();

    // ---- W2 GEMM: K=512, kh halves of 32 kt, dual accumulators ----
    f32x16 Cf0 = {}, Cf1 = {};
    for (int kt = kh * 32; kt < kh * 32 + 32; kt += 2) {
        h4 a0 = *(const h4*)&hid16[arow][kt * 8 + hf * 4];
        h4 b0 = *(const h4*)&W2B[((size_t)(kt * 4 + nt) * 64 + lane) * 4];
        Cf0 = __builtin_amdgcn_mfma_f32_32x32x8f16(a0, b0, Cf0, 0, 0, 0);
        h4 a1f = *(const h4*)&hid16[arow][(kt + 1) * 8 + hf * 4];
        h4 b1f = *(const h4*)&W2B[((size_t)((kt + 1) * 4 + nt) * 64 + lane) * 4];
        Cf1 = __builtin_amdgcn_mfma_f32_32x32x8f16(a1f, b1f, Cf1, 0, 0, 0);
    }
    if (kh == 0) {
#pragma unroll
        for (int r = 0; r < 8; r++)
            vL[(r & 3) + 8 * (r >> 2) + 4 * hf][nt * 32 + col] = Cf0[r] + Cf1[r];
    }
    __syncthreads();
    if (kh == 1) {
#pragma unroll
        for (int r = 0; r < 8; r++)
            vL[(r & 3) + 8 * (r >> 2) + 4 * hf][nt * 32 + col] += Cf0[r] + Cf1[r];
    }
    __syncthreads();

    // ---- v2 = h1 + f -> hL; LN2; write h ----
    float v2[4];
#pragma unroll
    for (int t = 0; t < 4; t++) {
        int idx = g * 4 + t;
        v2[t] = h1[t] + vL[idx][e];
        hL[idx][e] = v2[t];
    }
    __syncthreads();
    {
        float sm = 0.f, sq = 0.f;
#pragma unroll
        for (int i = 0; i < 4; i++) {
            float x = hL[tt][l32 + 32 * i];
            sm += x; sq += x * x;
        }
#pragma unroll
        for (int ofs = 16; ofs >= 1; ofs >>= 1) {
            sm += __shfl_xor(sm, ofs);
            sq += __shfl_xor(sq, ofs);
        }
        if (l32 == 0) {
            float mu = sm * (1.f / 128.f);
            meanL[tt] = mu;
            rstdL[tt] = rsqrtf(sq * (1.f / 128.f) - mu * mu + 1e-5f);
        }
    }
    __syncthreads();
    float ge2 = ln2g[e], be2 = ln2b[e];
#pragma unroll
    for (int t = 0; t < 4; t++) {
        int idx = g * 4 + t;
        h[(size_t)(t0 + idx) * 128 + e] = (v2[t] - meanL[idx]) * rstdL[idx] * ge2 + be2;
    }
}

// ---------------------------------------------------------------------------
// pooled = mean_s h; out = pooled @ Wc^T + bc.  8 blocks x 256 threads.
// ---------------------------------------------------------------------------
__global__ __launch_bounds__(256) void head_kernel(
    const float* __restrict__ h, const float* __restrict__ Wc,
    const float* __restrict__ bc, float* __restrict__ out)
{
    __shared__ float4 red[8][32];
    __shared__ float pooled[EE];
    int b = blockIdx.x, tid = threadIdx.x;
    int eq = tid & 31, sg = tid >> 5;
    const float4* h4p = (const float4*)h + (size_t)b * SS * 32;
    float4 acc = make_float4(0, 0, 0, 0);
    for (int r = 0; r < 64; r++) {
        int s = r * 8 + sg;
        float4 x = h4p[(size_t)s * 32 + eq];
        acc.x += x.x; acc.y += x.y; acc.z += x.z; acc.w += x.w;
    }
    red[sg][eq] = acc;
    __syncthreads();
    if (sg == 0) {
        float4 a = red[0][eq];
#pragma unroll
        for (int i = 1; i < 8; i++) {
            float4 x = red[i][eq];
            a.x += x.x; a.y += x.y; a.z += x.z; a.w += x.w;
        }
        const float s = 1.f / (float)SS;
        *(float4*)&pooled[eq * 4] = make_float4(a.x * s, a.y * s, a.z * s, a.w * s);
    }
    __syncthreads();
    if (tid < 160) {
        int c = tid >> 4, l16 = tid & 15;
        float p = 0.f;
#pragma unroll
        for (int i = 0; i < 8; i++) {
            int k = l16 + i * 16;
            p += pooled[k] * Wc[(size_t)c * EE + k];
        }
#pragma unroll
        for (int ofs = 8; ofs >= 1; ofs >>= 1) p += __shfl_xor(p, ofs);
        if (l16 == 0) out[b * CC + c] = p + bc[c];
    }
}

// ---------------------------------------------------------------------------
extern "C" void kernel_launch(void* const* d_in, const int* in_sizes, int n_in,
                              void* d_out, int out_size, void* d_ws, size_t ws_size,
                              hipStream_t stream)
{
    const int*   tokens     = (const int*)d_in[0];
    const float* emb        = (const float*)d_in[1];
    const float* attn_theta = (const float*)d_in[2];
    const float* ffn_theta  = (const float*)d_in[3];
    const float* Wo         = (const float*)d_in[4];
    const float* W1         = (const float*)d_in[5];
    const float* W2         = (const float*)d_in[6];
    const float* ln1g       = (const float*)d_in[7];
    const float* ln1b       = (const float*)d_in[8];
    const float* ln2g       = (const float*)d_in[9];
    const float* ln2b       = (const float*)d_in[10];
    const float* Wc         = (const float*)d_in[11];
    const float* bc         = (const float*)d_in[12];
    float* out = (float*)d_out;

    float* ws  = (float*)d_ws;
    float* h   = ws;                               // 524288 floats
    float* a1  = ws + 524288;                      // 524288
    float* a2  = ws + 1048576;                     // 524288
    float* s1  = ws + 1572864;                     // 65536
    float* s2  = ws + 1638400;                     // 65536
    _Float16* WoB = (_Float16*)(ws + 1703936);     // 65536 halves
    _Float16* W2B = (_Float16*)(ws + 1736704);     // 262144 halves

    prep_kernel<<<dim3(2048), dim3(256), 0, stream>>>(tokens, emb, Wo, W2, h, WoB, W2B);

    for (int l = 0; l < LL; l++) {
        attn_kernel<<<dim3(1024), dim3(256), 0, stream>>>(
            h, attn_theta + (size_t)l * 8, a1, a2, s1, s2);
        fused_kernel<<<dim3(256), dim3(512), 0, stream>>>(
            h, a1, a2, s1, s2,
            WoB + (size_t)l * 16384,
            W2B + (size_t)l * 65536,
            W1 + (size_t)l * 2048,
            ffn_theta + (size_t)l * 4,
            ln1g + (size_t)l * EE, ln1b + (size_t)l * EE,
            ln2g + (size_t)l * EE, ln2b + (size_t)l * EE);
    }

    head_kernel<<<dim3(BB), dim3(256), 0, stream>>>(h, Wc, bc, out);
}

// Round 11
// 99.635 us; speedup vs baseline: 4.3291x; 1.0280x over previous
//
#include <hip/hip_runtime.h>
#include <math.h>

// Problem dims
#define BB  8
#define SS  512
#define EE  128
#define HH  16
#define LL  4
#define FF  512
#define CC  10

typedef _Float16 h2 __attribute__((ext_vector_type(2)));
typedef _Float16 h4 __attribute__((ext_vector_type(4)));
typedef float f32x16 __attribute__((ext_vector_type(16)));

// ---------------------------------------------------------------------------
// fast cos: cos(x) = v_cos(fract(x / 2pi))  (v_cos takes revolutions)
// ---------------------------------------------------------------------------
__device__ __forceinline__ float fastcos(float x)
{
    float r = x * 0.15915494309189535f;
    asm("v_fract_f32 %0, %1" : "=v"(r) : "v"(r));
    float c;
    asm("v_cos_f32 %0, %1" : "=v"(c) : "v"(r));
    return c;
}

// ---------------------------------------------------------------------------
// prep: embed + f16 B-fragment swizzles for the fused MFMA GEMMs.
// WoB[l][kt(16)][nt(4)][lane(64)][jj(4)] = Wo[l][e][k], e=nt*32+(lane&31),
//      k=kt*8+(lane>>5)*4+jj
// W2B[l][kt(64)][nt(4)][lane(64)][jj(4)] = W2[l][e][j]
// ---------------------------------------------------------------------------
__global__ __launch_bounds__(256) void prep_kernel(
    const int* __restrict__ tokens, const float* __restrict__ emb,
    const float* __restrict__ Wo, const float* __restrict__ W2,
    float* __restrict__ h, _Float16* __restrict__ WoB, _Float16* __restrict__ W2B)
{
    int i = blockIdx.x * 256 + threadIdx.x;
    {
        int e  = i & 127;
        int bs = i >> 7;
        int s  = bs & 511;
        int tok = tokens[bs];
        int half = e >> 1;
        float ang = (float)s * expf(-0.07195578415606394f * (float)(2 * half));
        float pe  = (e & 1) ? cosf(ang) : sinf(ang);
        h[i] = emb[(size_t)tok * EE + e] + pe;
    }
    if (i < LL * 16384) {
        int jj = i & 3, lane = (i >> 2) & 63, nt = (i >> 8) & 3,
            kt = (i >> 10) & 15, l = i >> 14;
        int e = nt * 32 + (lane & 31);
        int k = kt * 8 + (lane >> 5) * 4 + jj;
        WoB[i] = (_Float16)Wo[((size_t)l * EE + e) * EE + k];
    }
    if (i < LL * 65536) {
        int jj = i & 3, lane = (i >> 2) & 63, nt = (i >> 8) & 3,
            kt = (i >> 10) & 63, l = i >> 16;
        int e = nt * 32 + (lane & 31);
        int j = kt * 8 + (lane >> 5) * 4 + jj;
        W2B[i] = (_Float16)W2[((size_t)l * EE + e) * FF + j];
    }
}

// ---------------------------------------------------------------------------
// ring measurement from raw x, fast-cos version
// ---------------------------------------------------------------------------
__device__ __forceinline__ void ring_from_x_fast(
    const float4 xa, const float4 xb, const float4 tha, const float4 thb,
    float* o)
{
    float c0 = fastcos(xa.x + tha.x), c1 = fastcos(xa.y + tha.y),
          c2 = fastcos(xa.z + tha.z), c3 = fastcos(xa.w + tha.w),
          c4 = fastcos(xb.x + thb.x), c5 = fastcos(xb.y + thb.y),
          c6 = fastcos(xb.z + thb.z), c7 = fastcos(xb.w + thb.w);
    o[0] = c1 * c2 * c3 * c4 * c5 * c6 * c7;   // z0 (no c0)
    float cum = c0;
    cum *= c1; o[1] = cum;  cum *= c2; o[2] = cum;
    cum *= c3; o[3] = cum;  cum *= c4; o[4] = cum;
    cum *= c5; o[5] = cum;  cum *= c6; o[6] = cum;
    cum *= c7; o[7] = cum;
}

// ---------------------------------------------------------------------------
// MFMA attention (r9-validated). grid = 128 bh x 4 qparts = 512 blocks,
// 256 thr (4 waves). Single-shot over all 512 keys (no key split: staging
// done once, query enc read from LDS). fastcos staging, packed encT writes.
// Per 32-key tile: S^T = mfma_32x32x8_f16(enc_k, enc_q); w = exp2(C*SC)
// (single-pass, |C*SC|<=4.08); packed f16 w-regs == PV A-operand exactly;
// V-aug ones column (col 8) -> rowsum free.
// ---------------------------------------------------------------------------
__global__ __launch_bounds__(256, 2) void attn_kernel(
    const float* __restrict__ h, const float* __restrict__ theta8,
    float* __restrict__ o)
{
    __shared__ _Float16 encA[2][SS][4];      // 8 KB
    __shared__ _Float16 encT[9][524];        // 9.2 KB
    int blk = blockIdx.x;
    int bh = blk >> 2, qpart = blk & 3;
    int b = bh >> 4, hh = bh & 15;
    int tid = threadIdx.x;

    float4 tha = ((const float4*)theta8)[0];
    float4 thb = ((const float4*)theta8)[1];

    // stage 512 keys: thread owns adjacent keys 2*tid, 2*tid+1
    {
        int k0 = 2 * tid;
        const float* hp0 = h + ((size_t)(b * SS + k0) * EE + hh * 8);
        const float* hp1 = hp0 + EE;
        float o0[8], o1[8];
        ring_from_x_fast(*(const float4*)hp0, *(const float4*)(hp0 + 4), tha, thb, o0);
        ring_from_x_fast(*(const float4*)hp1, *(const float4*)(hp1 + 4), tha, thb, o1);
        h4 lo0 = {(_Float16)o0[0], (_Float16)o0[1], (_Float16)o0[2], (_Float16)o0[3]};
        h4 hi0 = {(_Float16)o0[4], (_Float16)o0[5], (_Float16)o0[6], (_Float16)o0[7]};
        h4 lo1 = {(_Float16)o1[0], (_Float16)o1[1], (_Float16)o1[2], (_Float16)o1[3]};
        h4 hi1 = {(_Float16)o1[4], (_Float16)o1[5], (_Float16)o1[6], (_Float16)o1[7]};
        *(h4*)&encA[0][k0][0]     = lo0;
        *(h4*)&encA[0][k0 + 1][0] = lo1;
        *(h4*)&encA[1][k0][0]     = hi0;
        *(h4*)&encA[1][k0 + 1][0] = hi1;
#pragma unroll
        for (int d = 0; d < 8; d++) {
            h2 pr = {(_Float16)o0[d], (_Float16)o1[d]};
            *(h2*)&encT[d][k0] = pr;
        }
        h2 one2 = {(_Float16)1.0f, (_Float16)1.0f};
        *(h2*)&encT[8][k0] = one2;
    }
    __syncthreads();

    int lane = tid & 63, wv = tid >> 6;
    int col = lane & 31, hf = lane >> 5;
    int qtile = qpart * 128 + wv * 32;

    h4 bq = *(const h4*)&encA[hf][qtile + col][0];

    const float SC = 0.35355339059327373f * 1.4426950408889634f; // 1/sqrt(8)*log2e
    f32x16 Oacc = {};
    for (int kt = 0; kt < SS; kt += 32) {
        h4 ak = *(const h4*)&encA[hf][kt + col][0];
        f32x16 Cz = {};
        f32x16 C = __builtin_amdgcn_mfma_f32_32x32x8f16(ak, bq, Cz, 0, 0, 0);
        h2 ph[8];
#pragma unroll
        for (int r = 0; r < 16; r += 2) {
            float x0 = C[r] * SC, x1 = C[r + 1] * SC;
            float w0, w1;
            asm("v_exp_f32 %0, %1" : "=v"(w0) : "v"(x0));
            asm("v_exp_f32 %0, %1" : "=v"(w1) : "v"(x1));
            ph[r >> 1] = (h2)__builtin_amdgcn_cvt_pkrtz(w0, w1);
        }
#pragma unroll
        for (int j = 0; j < 4; j++) {
            h4 ap = {ph[2 * j][0], ph[2 * j][1], ph[2 * j + 1][0], ph[2 * j + 1][1]};
            h4 bv = {};
            if (col <= 8)
                bv = *(const h4*)&encT[col][kt + 8 * j + 4 * hf];
            Oacc = __builtin_amdgcn_mfma_f32_32x32x8f16(ap, bv, Oacc, 0, 0, 0);
        }
    }

#pragma unroll
    for (int r = 0; r < 16; r++) {
        float rs  = __shfl(Oacc[r], 8, 32);
        float inv = __builtin_amdgcn_rcpf(rs);
        if (col < 8) {
            int q = qtile + (r & 3) + 8 * (r >> 2) + 4 * hf;
            o[((size_t)(b * SS + q)) * EE + hh * 8 + col] = Oacc[r] * inv;
        }
    }
}

// ---------------------------------------------------------------------------
// Fused (r6-validated geometry + r10-validated dual-acc): 16 tokens/block,
// 512 threads (8 waves: nt = wv&3 e-tile, kh = wv>>2 K-half), grid 256.
// MFMA rows 16-31 junk -> confined to C rows 16-31, never stored.
// ---------------------------------------------------------------------------
__global__ __launch_bounds__(512, 2) void fused_kernel(
    float* __restrict__ h, const float* __restrict__ o,
    const _Float16* __restrict__ WoB, const _Float16* __restrict__ W2B,
    const float* __restrict__ W1, const float* __restrict__ ffn_theta,
    const float* __restrict__ ln1g, const float* __restrict__ ln1b,
    const float* __restrict__ ln2g, const float* __restrict__ ln2b)
{
    __shared__ _Float16 oA[32][132];
    __shared__ _Float16 hid16[32][516];
    __shared__ float vL[16][128];
    __shared__ float hL[16][128];
    __shared__ __align__(16) float measL[16][4];
    __shared__ float meanL[16], rstdL[16];

    int tid = threadIdx.x;
    int t0  = blockIdx.x * 16;

    // stage o (f32->f16 A layout) + h residual
    {
        int t = tid >> 5, c4 = tid & 31;
        float4 ov = ((const float4*)o)[(size_t)(t0 + t) * 32 + c4];
        h4 hv = {(_Float16)ov.x, (_Float16)ov.y, (_Float16)ov.z, (_Float16)ov.w};
        *(h4*)&oA[t][c4 * 4] = hv;
        float4 hvf = ((const float4*)h)[(size_t)(t0 + t) * 32 + c4];
        *(float4*)&hL[t][c4 * 4] = hvf;
    }
    __syncthreads();

    int lane = tid & 63, wv = tid >> 6;
    int arow = lane & 31, hf = lane >> 5;
    int col  = lane & 31;
    int nt = wv & 3, kh = wv >> 2;

    // ---- Wo GEMM: K=128, kh halves of 8 kt, dual accumulators ----
    f32x16 Cw0 = {}, Cw1 = {};
    for (int kt = kh * 8; kt < kh * 8 + 8; kt += 2) {
        h4 a0 = *(const h4*)&oA[arow][kt * 8 + hf * 4];
        h4 b0 = *(const h4*)&WoB[((size_t)(kt * 4 + nt) * 64 + lane) * 4];
        Cw0 = __builtin_amdgcn_mfma_f32_32x32x8f16(a0, b0, Cw0, 0, 0, 0);
        h4 a1 = *(const h4*)&oA[arow][(kt + 1) * 8 + hf * 4];
        h4 b1 = *(const h4*)&WoB[((size_t)((kt + 1) * 4 + nt) * 64 + lane) * 4];
        Cw1 = __builtin_amdgcn_mfma_f32_32x32x8f16(a1, b1, Cw1, 0, 0, 0);
    }
    if (kh == 0) {
#pragma unroll
        for (int r = 0; r < 8; r++)
            vL[(r & 3) + 8 * (r >> 2) + 4 * hf][nt * 32 + col] = Cw0[r] + Cw1[r];
    }
    __syncthreads();
    if (kh == 1) {
#pragma unroll
        for (int r = 0; r < 8; r++)
            vL[(r & 3) + 8 * (r >> 2) + 4 * hf][nt * 32 + col] += Cw0[r] + Cw1[r];
    }
    __syncthreads();

    // ---- LN1 stats: 32 lanes/token ----
    int tt = tid >> 5, l32 = tid & 31;
    {
        float sm = 0.f, sq = 0.f;
#pragma unroll
        for (int i = 0; i < 4; i++) {
            float x = vL[tt][l32 + 32 * i] + hL[tt][l32 + 32 * i];
            sm += x; sq += x * x;
        }
#pragma unroll
        for (int ofs = 16; ofs >= 1; ofs >>= 1) {
            sm += __shfl_xor(sm, ofs);
            sq += __shfl_xor(sq, ofs);
        }
        if (l32 == 0) {
            float mu = sm * (1.f / 128.f);
            meanL[tt] = mu;
            rstdL[tt] = rsqrtf(sq * (1.f / 128.f) - mu * mu + 1e-5f);
        }
    }
    __syncthreads();

    int e = tid & 127, g = tid >> 7;
    float ge1 = ln1g[e], be1 = ln1b[e];
    float h1[4];
#pragma unroll
    for (int t = 0; t < 4; t++) {
        int idx = g * 4 + t;
        float v = vL[idx][e] + hL[idx][e];
        h1[t] = (v - meanL[idx]) * rstdL[idx] * ge1 + be1;
    }
    if (e < 4) {
        float cth = cosf(ffn_theta[e]);
#pragma unroll
        for (int t = 0; t < 4; t++) measL[g * 4 + t][e] = cosf(h1[t]) * cth;
    }
    __syncthreads();

    // ---- hidden = relu(meas @ W1^T) -> f16 A layout; thread owns j=tid ----
    {
        float4 w1v = ((const float4*)W1)[tid];
#pragma unroll
        for (int t = 0; t < 16; t++) {
            float4 mv = *(const float4*)&measL[t][0];
            float hv = mv.x * w1v.x + mv.y * w1v.y + mv.z * w1v.z + mv.w * w1v.w;
            hid16[t][tid] = (_Float16)fmaxf(hv, 0.f);
        }
    }
    __syncthreads();

    // ---- W2 GEMM: K=512, kh halves of 32 kt, dual accumulators ----
    f32x16 Cf0 = {}, Cf1 = {};
    for (int kt = kh * 32; kt < kh * 32 + 32; kt += 2) {
        h4 a0 = *(const h4*)&hid16[arow][kt * 8 + hf * 4];
        h4 b0 = *(const h4*)&W2B[((size_t)(kt * 4 + nt) * 64 + lane) * 4];
        Cf0 = __builtin_amdgcn_mfma_f32_32x32x8f16(a0, b0, Cf0, 0, 0, 0);
        h4 a1f = *(const h4*)&hid16[arow][(kt + 1) * 8 + hf * 4];
        h4 b1f = *(const h4*)&W2B[((size_t)((kt + 1) * 4 + nt) * 64 + lane) * 4];
        Cf1 = __builtin_amdgcn_mfma_f32_32x32x8f16(a1f, b1f, Cf1, 0, 0, 0);
    }
    if (kh == 0) {
#pragma unroll
        for (int r = 0; r < 8; r++)
            vL[(r & 3) + 8 * (r >> 2) + 4 * hf][nt * 32 + col] = Cf0[r] + Cf1[r];
    }
    __syncthreads();
    if (kh == 1) {
#pragma unroll
        for (int r = 0; r < 8; r++)
            vL[(r & 3) + 8 * (r >> 2) + 4 * hf][nt * 32 + col] += Cf0[r] + Cf1[r];
    }
    __syncthreads();

    // ---- v2 = h1 + f -> hL; LN2; write h ----
    float v2[4];
#pragma unroll
    for (int t = 0; t < 4; t++) {
        int idx = g * 4 + t;
        v2[t] = h1[t] + vL[idx][e];
        hL[idx][e] = v2[t];
    }
    __syncthreads();
    {
        float sm = 0.f, sq = 0.f;
#pragma unroll
        for (int i = 0; i < 4; i++) {
            float x = hL[tt][l32 + 32 * i];
            sm += x; sq += x * x;
        }
#pragma unroll
        for (int ofs = 16; ofs >= 1; ofs >>= 1) {
            sm += __shfl_xor(sm, ofs);
            sq += __shfl_xor(sq, ofs);
        }
        if (l32 == 0) {
            float mu = sm * (1.f / 128.f);
            meanL[tt] = mu;
            rstdL[tt] = rsqrtf(sq * (1.f / 128.f) - mu * mu + 1e-5f);
        }
    }
    __syncthreads();
    float ge2 = ln2g[e], be2 = ln2b[e];
#pragma unroll
    for (int t = 0; t < 4; t++) {
        int idx = g * 4 + t;
        h[(size_t)(t0 + idx) * 128 + e] = (v2[t] - meanL[idx]) * rstdL[idx] * ge2 + be2;
    }
}

// ---------------------------------------------------------------------------
// pooled = mean_s h; out = pooled @ Wc^T + bc.  8 blocks x 256 threads.
// ---------------------------------------------------------------------------
__global__ __launch_bounds__(256) void head_kernel(
    const float* __restrict__ h, const float* __restrict__ Wc,
    const float* __restrict__ bc, float* __restrict__ out)
{
    __shared__ float4 red[8][32];
    __shared__ float pooled[EE];
    int b = blockIdx.x, tid = threadIdx.x;
    int eq = tid & 31, sg = tid >> 5;
    const float4* h4p = (const float4*)h + (size_t)b * SS * 32;
    float4 acc = make_float4(0, 0, 0, 0);
    for (int r = 0; r < 64; r++) {
        int s = r * 8 + sg;
        float4 x = h4p[(size_t)s * 32 + eq];
        acc.x += x.x; acc.y += x.y; acc.z += x.z; acc.w += x.w;
    }
    red[sg][eq] = acc;
    __syncthreads();
    if (sg == 0) {
        float4 a = red[0][eq];
#pragma unroll
        for (int i = 1; i < 8; i++) {
            float4 x = red[i][eq];
            a.x += x.x; a.y += x.y; a.z += x.z; a.w += x.w;
        }
        const float s = 1.f / (float)SS;
        *(float4*)&pooled[eq * 4] = make_float4(a.x * s, a.y * s, a.z * s, a.w * s);
    }
    __syncthreads();
    if (tid < 160) {
        int c = tid >> 4, l16 = tid & 15;
        float p = 0.f;
#pragma unroll
        for (int i = 0; i < 8; i++) {
            int k = l16 + i * 16;
            p += pooled[k] * Wc[(size_t)c * EE + k];
        }
#pragma unroll
        for (int ofs = 8; ofs >= 1; ofs >>= 1) p += __shfl_xor(p, ofs);
        if (l16 == 0) out[b * CC + c] = p + bc[c];
    }
}

// ---------------------------------------------------------------------------
extern "C" void kernel_launch(void* const* d_in, const int* in_sizes, int n_in,
                              void* d_out, int out_size, void* d_ws, size_t ws_size,
                              hipStream_t stream)
{
    const int*   tokens     = (const int*)d_in[0];
    const float* emb        = (const float*)d_in[1];
    const float* attn_theta = (const float*)d_in[2];
    const float* ffn_theta  = (const float*)d_in[3];
    const float* Wo         = (const float*)d_in[4];
    const float* W1         = (const float*)d_in[5];
    const float* W2         = (const float*)d_in[6];
    const float* ln1g       = (const float*)d_in[7];
    const float* ln1b       = (const float*)d_in[8];
    const float* ln2g       = (const float*)d_in[9];
    const float* ln2b       = (const float*)d_in[10];
    const float* Wc         = (const float*)d_in[11];
    const float* bc         = (const float*)d_in[12];
    float* out = (float*)d_out;

    float* ws  = (float*)d_ws;
    float* h   = ws;                               // 524288 floats
    float* o   = ws + 524288;                      // 524288 floats
    _Float16* WoB = (_Float16*)(ws + 1048576);     // 65536 halves
    _Float16* W2B = (_Float16*)(ws + 1081344);     // 262144 halves

    prep_kernel<<<dim3(2048), dim3(256), 0, stream>>>(tokens, emb, Wo, W2, h, WoB, W2B);

    for (int l = 0; l < LL; l++) {
        attn_kernel<<<dim3(512), dim3(256), 0, stream>>>(
            h, attn_theta + (size_t)l * 8, o);
        fused_kernel<<<dim3(256), dim3(512), 0, stream>>>(
            h, o,
            WoB + (size_t)l * 16384,
            W2B + (size_t)l * 65536,
            W1 + (size_t)l * 2048,
            ffn_theta + (size_t)l * 4,
            ln1g + (size_t)l * EE, ln1b + (size_t)l * EE,
            ln2g + (size_t)l * EE, ln2b + (size_t)l * EE);
    }

    head_kernel<<<dim3(BB), dim3(256), 0, stream>>>(h, Wc, bc, out);
}

// Round 12
// 99.067 us; speedup vs baseline: 4.3539x; 1.0057x over previous
//
#include <hip/hip_runtime.h>
#include <math.h>

// Problem dims
#define BB  8
#define SS  512
#define EE  128
#define HH  16
#define LL  4
#define FF  512
#define CC  10

typedef _Float16 h2 __attribute__((ext_vector_type(2)));
typedef _Float16 h4 __attribute__((ext_vector_type(4)));
typedef float f32x16 __attribute__((ext_vector_type(16)));

// ---------------------------------------------------------------------------
// fast trig: v_cos/v_sin take revolutions; reduce with v_fract first.
// ---------------------------------------------------------------------------
__device__ __forceinline__ float fastcos(float x)
{
    float r = x * 0.15915494309189535f;
    asm("v_fract_f32 %0, %1" : "=v"(r) : "v"(r));
    float c;
    asm("v_cos_f32 %0, %1" : "=v"(c) : "v"(r));
    return c;
}
__device__ __forceinline__ float fastsin(float x)
{
    float r = x * 0.15915494309189535f;
    asm("v_fract_f32 %0, %1" : "=v"(r) : "v"(r));
    float s;
    asm("v_sin_f32 %0, %1" : "=v"(s) : "v"(r));
    return s;
}

// ---------------------------------------------------------------------------
// prep: embed (cheap-math PE) + f16 B-fragment swizzles for fused GEMMs.
// WoB[l][kt(16)][nt(4)][lane(64)][jj(4)] = Wo[l][e][k], e=nt*32+(lane&31),
//      k=kt*8+(lane>>5)*4+jj
// W2B[l][kt(64)][nt(4)][lane(64)][jj(4)] = W2[l][e][j]
// ---------------------------------------------------------------------------
__global__ __launch_bounds__(256) void prep_kernel(
    const int* __restrict__ tokens, const float* __restrict__ emb,
    const float* __restrict__ Wo, const float* __restrict__ W2,
    float* __restrict__ h, _Float16* __restrict__ WoB, _Float16* __restrict__ W2B)
{
    int i = blockIdx.x * 256 + threadIdx.x;
    {
        int e  = i & 127;
        int bs = i >> 7;
        int s  = bs & 511;
        int tok = tokens[bs];
        int half = e >> 1;
        // div = 10000^(-2*half/128) = exp2(half * -log2(10000)/64)
        float div;
        asm("v_exp_f32 %0, %1" : "=v"(div) : "v"(half * -0.2076241918f));
        float ang = (float)s * div;
        float pe  = (e & 1) ? fastcos(ang) : fastsin(ang);
        h[i] = emb[(size_t)tok * EE + e] + pe;
    }
    if (i < LL * 16384) {
        int jj = i & 3, lane = (i >> 2) & 63, nt = (i >> 8) & 3,
            kt = (i >> 10) & 15, l = i >> 14;
        int e = nt * 32 + (lane & 31);
        int k = kt * 8 + (lane >> 5) * 4 + jj;
        WoB[i] = (_Float16)Wo[((size_t)l * EE + e) * EE + k];
    }
    if (i < LL * 65536) {
        int jj = i & 3, lane = (i >> 2) & 63, nt = (i >> 8) & 3,
            kt = (i >> 10) & 63, l = i >> 16;
        int e = nt * 32 + (lane & 31);
        int j = kt * 8 + (lane >> 5) * 4 + jj;
        W2B[i] = (_Float16)W2[((size_t)l * EE + e) * FF + j];
    }
}

// ---------------------------------------------------------------------------
// ring measurement from raw x, fast-cos version
// ---------------------------------------------------------------------------
__device__ __forceinline__ void ring_from_x_fast(
    const float4 xa, const float4 xb, const float4 tha, const float4 thb,
    float* o)
{
    float c0 = fastcos(xa.x + tha.x), c1 = fastcos(xa.y + tha.y),
          c2 = fastcos(xa.z + tha.z), c3 = fastcos(xa.w + tha.w),
          c4 = fastcos(xb.x + thb.x), c5 = fastcos(xb.y + thb.y),
          c6 = fastcos(xb.z + thb.z), c7 = fastcos(xb.w + thb.w);
    o[0] = c1 * c2 * c3 * c4 * c5 * c6 * c7;   // z0 (no c0)
    float cum = c0;
    cum *= c1; o[1] = cum;  cum *= c2; o[2] = cum;
    cum *= c3; o[3] = cum;  cum *= c4; o[4] = cum;
    cum *= c5; o[5] = cum;  cum *= c6; o[6] = cum;
    cum *= c7; o[7] = cum;
}

// ---------------------------------------------------------------------------
// MFMA attention (r9/r11-validated structure) + dual PV accumulators.
// grid = 128 bh x 4 qparts = 512 blocks, 256 thr (4 waves).
// Per 32-key tile: S^T = mfma_32x32x8_f16(enc_k, enc_q); w = exp2(C*SC)
// (single-pass, |C*SC|<=4.08); packed f16 w-regs == PV A-operand exactly;
// V-aug ones column (col 8) -> rowsum free. PV j=0,2 -> O0; j=1,3 -> O1
// (independent MFMA dep-chains, merged in epilogue).
// ---------------------------------------------------------------------------
__global__ __launch_bounds__(256, 2) void attn_kernel(
    const float* __restrict__ h, const float* __restrict__ theta8,
    float* __restrict__ o)
{
    __shared__ _Float16 encA[2][SS][4];      // 8 KB
    __shared__ _Float16 encT[9][524];        // 9.2 KB
    int blk = blockIdx.x;
    int bh = blk >> 2, qpart = blk & 3;
    int b = bh >> 4, hh = bh & 15;
    int tid = threadIdx.x;

    float4 tha = ((const float4*)theta8)[0];
    float4 thb = ((const float4*)theta8)[1];

    // stage 512 keys: thread owns adjacent keys 2*tid, 2*tid+1
    {
        int k0 = 2 * tid;
        const float* hp0 = h + ((size_t)(b * SS + k0) * EE + hh * 8);
        const float* hp1 = hp0 + EE;
        float o0[8], o1[8];
        ring_from_x_fast(*(const float4*)hp0, *(const float4*)(hp0 + 4), tha, thb, o0);
        ring_from_x_fast(*(const float4*)hp1, *(const float4*)(hp1 + 4), tha, thb, o1);
        h4 lo0 = {(_Float16)o0[0], (_Float16)o0[1], (_Float16)o0[2], (_Float16)o0[3]};
        h4 hi0 = {(_Float16)o0[4], (_Float16)o0[5], (_Float16)o0[6], (_Float16)o0[7]};
        h4 lo1 = {(_Float16)o1[0], (_Float16)o1[1], (_Float16)o1[2], (_Float16)o1[3]};
        h4 hi1 = {(_Float16)o1[4], (_Float16)o1[5], (_Float16)o1[6], (_Float16)o1[7]};
        *(h4*)&encA[0][k0][0]     = lo0;
        *(h4*)&encA[0][k0 + 1][0] = lo1;
        *(h4*)&encA[1][k0][0]     = hi0;
        *(h4*)&encA[1][k0 + 1][0] = hi1;
#pragma unroll
        for (int d = 0; d < 8; d++) {
            h2 pr = {(_Float16)o0[d], (_Float16)o1[d]};
            *(h2*)&encT[d][k0] = pr;
        }
        h2 one2 = {(_Float16)1.0f, (_Float16)1.0f};
        *(h2*)&encT[8][k0] = one2;
    }
    __syncthreads();

    int lane = tid & 63, wv = tid >> 6;
    int col = lane & 31, hf = lane >> 5;
    int qtile = qpart * 128 + wv * 32;

    h4 bq = *(const h4*)&encA[hf][qtile + col][0];

    const float SC = 0.35355339059327373f * 1.4426950408889634f; // 1/sqrt(8)*log2e
    f32x16 O0 = {}, O1 = {};
    for (int kt = 0; kt < SS; kt += 32) {
        h4 ak = *(const h4*)&encA[hf][kt + col][0];
        f32x16 Cz = {};
        f32x16 C = __builtin_amdgcn_mfma_f32_32x32x8f16(ak, bq, Cz, 0, 0, 0);
        h2 ph[8];
#pragma unroll
        for (int r = 0; r < 16; r += 2) {
            float x0 = C[r] * SC, x1 = C[r + 1] * SC;
            float w0, w1;
            asm("v_exp_f32 %0, %1" : "=v"(w0) : "v"(x0));
            asm("v_exp_f32 %0, %1" : "=v"(w1) : "v"(x1));
            ph[r >> 1] = (h2)__builtin_amdgcn_cvt_pkrtz(w0, w1);
        }
#pragma unroll
        for (int j = 0; j < 4; j++) {
            h4 ap = {ph[2 * j][0], ph[2 * j][1], ph[2 * j + 1][0], ph[2 * j + 1][1]};
            h4 bv = {};
            if (col <= 8)
                bv = *(const h4*)&encT[col][kt + 8 * j + 4 * hf];
            if (j & 1)
                O1 = __builtin_amdgcn_mfma_f32_32x32x8f16(ap, bv, O1, 0, 0, 0);
            else
                O0 = __builtin_amdgcn_mfma_f32_32x32x8f16(ap, bv, O0, 0, 0, 0);
        }
    }

#pragma unroll
    for (int r = 0; r < 16; r++) {
        float ov = O0[r] + O1[r];
        float rs = __shfl(ov, 8, 32);
        float inv = __builtin_amdgcn_rcpf(rs);
        if (col < 8) {
            int q = qtile + (r & 3) + 8 * (r >> 2) + 4 * hf;
            o[((size_t)(b * SS + q)) * EE + hh * 8 + col] = ov * inv;
        }
    }
}

// ---------------------------------------------------------------------------
// Fused (r6-validated geometry + r10-validated dual-acc): 16 tokens/block,
// 512 threads (8 waves: nt = wv&3 e-tile, kh = wv>>2 K-half), grid 256.
// MFMA rows 16-31 junk -> confined to C rows 16-31, never stored.
// ---------------------------------------------------------------------------
__global__ __launch_bounds__(512, 2) void fused_kernel(
    float* __restrict__ h, const float* __restrict__ o,
    const _Float16* __restrict__ WoB, const _Float16* __restrict__ W2B,
    const float* __restrict__ W1, const float* __restrict__ ffn_theta,
    const float* __restrict__ ln1g, const float* __restrict__ ln1b,
    const float* __restrict__ ln2g, const float* __restrict__ ln2b)
{
    __shared__ _Float16 oA[32][132];
    __shared__ _Float16 hid16[32][516];
    __shared__ float vL[16][128];
    __shared__ float hL[16][128];
    __shared__ __align__(16) float measL[16][4];
    __shared__ float meanL[16], rstdL[16];

    int tid = threadIdx.x;
    int t0  = blockIdx.x * 16;

    // stage o (f32->f16 A layout) + h residual
    {
        int t = tid >> 5, c4 = tid & 31;
        float4 ov = ((const float4*)o)[(size_t)(t0 + t) * 32 + c4];
        h4 hv = {(_Float16)ov.x, (_Float16)ov.y, (_Float16)ov.z, (_Float16)ov.w};
        *(h4*)&oA[t][c4 * 4] = hv;
        float4 hvf = ((const float4*)h)[(size_t)(t0 + t) * 32 + c4];
        *(float4*)&hL[t][c4 * 4] = hvf;
    }
    __syncthreads();

    int lane = tid & 63, wv = tid >> 6;
    int arow = lane & 31, hf = lane >> 5;
    int col  = lane & 31;
    int nt = wv & 3, kh = wv >> 2;

    // ---- Wo GEMM: K=128, kh halves of 8 kt, dual accumulators ----
    f32x16 Cw0 = {}, Cw1 = {};
    for (int kt = kh * 8; kt < kh * 8 + 8; kt += 2) {
        h4 a0 = *(const h4*)&oA[arow][kt * 8 + hf * 4];
        h4 b0 = *(const h4*)&WoB[((size_t)(kt * 4 + nt) * 64 + lane) * 4];
        Cw0 = __builtin_amdgcn_mfma_f32_32x32x8f16(a0, b0, Cw0, 0, 0, 0);
        h4 a1 = *(const h4*)&oA[arow][(kt + 1) * 8 + hf * 4];
        h4 b1 = *(const h4*)&WoB[((size_t)((kt + 1) * 4 + nt) * 64 + lane) * 4];
        Cw1 = __builtin_amdgcn_mfma_f32_32x32x8f16(a1, b1, Cw1, 0, 0, 0);
    }
    if (kh == 0) {
#pragma unroll
        for (int r = 0; r < 8; r++)
            vL[(r & 3) + 8 * (r >> 2) + 4 * hf][nt * 32 + col] = Cw0[r] + Cw1[r];
    }
    __syncthreads();
    if (kh == 1) {
#pragma unroll
        for (int r = 0; r < 8; r++)
            vL[(r & 3) + 8 * (r >> 2) + 4 * hf][nt * 32 + col] += Cw0[r] + Cw1[r];
    }
    __syncthreads();

    // ---- LN1 stats: 32 lanes/token ----
    int tt = tid >> 5, l32 = tid & 31;
    {
        float sm = 0.f, sq = 0.f;
#pragma unroll
        for (int i = 0; i < 4; i++) {
            float x = vL[tt][l32 + 32 * i] + hL[tt][l32 + 32 * i];
            sm += x; sq += x * x;
        }
#pragma unroll
        for (int ofs = 16; ofs >= 1; ofs >>= 1) {
            sm += __shfl_xor(sm, ofs);
            sq += __shfl_xor(sq, ofs);
        }
        if (l32 == 0) {
            float mu = sm * (1.f / 128.f);
            meanL[tt] = mu;
            rstdL[tt] = rsqrtf(sq * (1.f / 128.f) - mu * mu + 1e-5f);
        }
    }
    __syncthreads();

    int e = tid & 127, g = tid >> 7;
    float ge1 = ln1g[e], be1 = ln1b[e];
    float h1[4];
#pragma unroll
    for (int t = 0; t < 4; t++) {
        int idx = g * 4 + t;
        float v = vL[idx][e] + hL[idx][e];
        h1[t] = (v - meanL[idx]) * rstdL[idx] * ge1 + be1;
    }
    if (e < 4) {
        float cth = cosf(ffn_theta[e]);
#pragma unroll
        for (int t = 0; t < 4; t++) measL[g * 4 + t][e] = cosf(h1[t]) * cth;
    }
    __syncthreads();

    // ---- hidden = relu(meas @ W1^T) -> f16 A layout; thread owns j=tid ----
    {
        float4 w1v = ((const float4*)W1)[tid];
#pragma unroll
        for (int t = 0; t < 16; t++) {
            float4 mv = *(const float4*)&measL[t][0];
            float hv = mv.x * w1v.x + mv.y * w1v.y + mv.z * w1v.z + mv.w * w1v.w;
            hid16[t][tid] = (_Float16)fmaxf(hv, 0.f);
        }
    }
    __syncthreads();

    // ---- W2 GEMM: K=512, kh halves of 32 kt, dual accumulators ----
    f32x16 Cf0 = {}, Cf1 = {};
    for (int kt = kh * 32; kt < kh * 32 + 32; kt += 2) {
        h4 a0 = *(const h4*)&hid16[arow][kt * 8 + hf * 4];
        h4 b0 = *(const h4*)&W2B[((size_t)(kt * 4 + nt) * 64 + lane) * 4];
        Cf0 = __builtin_amdgcn_mfma_f32_32x32x8f16(a0, b0, Cf0, 0, 0, 0);
        h4 a1f = *(const h4*)&hid16[arow][(kt + 1) * 8 + hf * 4];
        h4 b1f = *(const h4*)&W2B[((size_t)((kt + 1) * 4 + nt) * 64 + lane) * 4];
        Cf1 = __builtin_amdgcn_mfma_f32_32x32x8f16(a1f, b1f, Cf1, 0, 0, 0);
    }
    if (kh == 0) {
#pragma unroll
        for (int r = 0; r < 8; r++)
            vL[(r & 3) + 8 * (r >> 2) + 4 * hf][nt * 32 + col] = Cf0[r] + Cf1[r];
    }
    __syncthreads();
    if (kh == 1) {
#pragma unroll
        for (int r = 0; r < 8; r++)
            vL[(r & 3) + 8 * (r >> 2) + 4 * hf][nt * 32 + col] += Cf0[r] + Cf1[r];
    }
    __syncthreads();

    // ---- v2 = h1 + f -> hL; LN2; write h ----
    float v2[4];
#pragma unroll
    for (int t = 0; t < 4; t++) {
        int idx = g * 4 + t;
        v2[t] = h1[t] + vL[idx][e];
        hL[idx][e] = v2[t];
    }
    __syncthreads();
    {
        float sm = 0.f, sq = 0.f;
#pragma unroll
        for (int i = 0; i < 4; i++) {
            float x = hL[tt][l32 + 32 * i];
            sm += x; sq += x * x;
        }
#pragma unroll
        for (int ofs = 16; ofs >= 1; ofs >>= 1) {
            sm += __shfl_xor(sm, ofs);
            sq += __shfl_xor(sq, ofs);
        }
        if (l32 == 0) {
            float mu = sm * (1.f / 128.f);
            meanL[tt] = mu;
            rstdL[tt] = rsqrtf(sq * (1.f / 128.f) - mu * mu + 1e-5f);
        }
    }
    __syncthreads();
    float ge2 = ln2g[e], be2 = ln2b[e];
#pragma unroll
    for (int t = 0; t < 4; t++) {
        int idx = g * 4 + t;
        h[(size_t)(t0 + idx) * 128 + e] = (v2[t] - meanL[idx]) * rstdL[idx] * ge2 + be2;
    }
}

// ---------------------------------------------------------------------------
// pooled = mean_s h; out = pooled @ Wc^T + bc.  8 blocks x 256 threads.
// ---------------------------------------------------------------------------
__global__ __launch_bounds__(256) void head_kernel(
    const float* __restrict__ h, const float* __restrict__ Wc,
    const float* __restrict__ bc, float* __restrict__ out)
{
    __shared__ float4 red[8][32];
    __shared__ float pooled[EE];
    int b = blockIdx.x, tid = threadIdx.x;
    int eq = tid & 31, sg = tid >> 5;
    const float4* h4p = (const float4*)h + (size_t)b * SS * 32;
    float4 acc = make_float4(0, 0, 0, 0);
    for (int r = 0; r < 64; r++) {
        int s = r * 8 + sg;
        float4 x = h4p[(size_t)s * 32 + eq];
        acc.x += x.x; acc.y += x.y; acc.z += x.z; acc.w += x.w;
    }
    red[sg][eq] = acc;
    __syncthreads();
    if (sg == 0) {
        float4 a = red[0][eq];
#pragma unroll
        for (int i = 1; i < 8; i++) {
            float4 x = red[i][eq];
            a.x += x.x; a.y += x.y; a.z += x.z; a.w += x.w;
        }
        const float s = 1.f / (float)SS;
        *(float4*)&pooled[eq * 4] = make_float4(a.x * s, a.y * s, a.z * s, a.w * s);
    }
    __syncthreads();
    if (tid < 160) {
        int c = tid >> 4, l16 = tid & 15;
        float p = 0.f;
#pragma unroll
        for (int i = 0; i < 8; i++) {
            int k = l16 + i * 16;
            p += pooled[k] * Wc[(size_t)c * EE + k];
        }
#pragma unroll
        for (int ofs = 8; ofs >= 1; ofs >>= 1) p += __shfl_xor(p, ofs);
        if (l16 == 0) out[b * CC + c] = p + bc[c];
    }
}

// ---------------------------------------------------------------------------
extern "C" void kernel_launch(void* const* d_in, const int* in_sizes, int n_in,
                              void* d_out, int out_size, void* d_ws, size_t ws_size,
                              hipStream_t stream)
{
    const int*   tokens     = (const int*)d_in[0];
    const float* emb        = (const float*)d_in[1];
    const float* attn_theta = (const float*)d_in[2];
    const float* ffn_theta  = (const float*)d_in[3];
    const float* Wo         = (const float*)d_in[4];
    const float* W1         = (const float*)d_in[5];
    const float* W2         = (const float*)d_in[6];
    const float* ln1g       = (const float*)d_in[7];
    const float* ln1b       = (const float*)d_in[8];
    const float* ln2g       = (const float*)d_in[9];
    const float* ln2b       = (const float*)d_in[10];
    const float* Wc         = (const float*)d_in[11];
    const float* bc         = (const float*)d_in[12];
    float* out = (float*)d_out;

    float* ws  = (float*)d_ws;
    float* h   = ws;                               // 524288 floats
    float* o   = ws + 524288;                      // 524288 floats
    _Float16* WoB = (_Float16*)(ws + 1048576);     // 65536 halves
    _Float16* W2B = (_Float16*)(ws + 1081344);     // 262144 halves

    prep_kernel<<<dim3(2048), dim3(256), 0, stream>>>(tokens, emb, Wo, W2, h, WoB, W2B);

    for (int l = 0; l < LL; l++) {
        attn_kernel<<<dim3(512), dim3(256), 0, stream>>>(
            h, attn_theta + (size_t)l * 8, o);
        fused_kernel<<<dim3(256), dim3(512), 0, stream>>>(
            h, o,
            WoB + (size_t)l * 16384,
            W2B + (size_t)l * 65536,
            W1 + (size_t)l * 2048,
            ffn_theta + (size_t)l * 4,
            ln1g + (size_t)l * EE, ln1b + (size_t)l * EE,
            ln2g + (size_t)l * EE, ln2b + (size_t)l * EE);
    }

    head_kernel<<<dim3(BB), dim3(256), 0, stream>>>(h, Wc, bc, out);
}